// Round 4
// baseline (715.064 us; speedup 1.0000x reference)
//
// CrossAttentionBlock_56813827392085 — fused transformer block, bf16 MFMA internals. R10:
//  = R8 structure + per-shape loop choice, with two fixes over R9:
//  1) DE-TEMPLATED GEMMs: gemm_up (EPI2, SYNC loop) and gemm_dn (EPI3, CNT loop) are
//     separate kernels — R9's if(EPI) template branch polluted EPI3 regalloc (VGPR 84->92,
//     occupancy 26->20%). Rule: co-compiled variants perturb codegen.
//  2) CA q-proj MERGED into the CA kv dispatch (gemm_ca, grid 8x384 = 3072 blocks, 12/CU):
//     the standalone q dispatch was 512 blocks = 2 blocks/CU, latency-bound at MfmaUtil 20%.
//     x-LN staged in OUTB (free until apply writes it, stream-ordered).
//  Kept: counted-vmcnt CNT loop for qkv/dn (netted -44us in R8), SYNC loop for up-proj
//  (R9 proved <=64us vs CNT's 83), sigmoid gelu, XCD swizzle, fused dinv/colsum-softmax.
#include <hip/hip_runtime.h>
#include <hip/hip_bf16.h>
#include <math.h>
#include <stdint.h>

typedef unsigned short u16;
typedef __attribute__((ext_vector_type(8))) short bh8;
typedef __attribute__((ext_vector_type(4))) float fx4;

#define DEV static __device__ __forceinline__

DEV float bf2f(u16 u){ union{unsigned u; float f;} v; v.u = ((unsigned)u)<<16; return v.f; }
DEV u16 f2bf(float f){ union{float f; unsigned u;} v; v.f = f;
  return (u16)((v.u + 0x7fffu + ((v.u>>16)&1u))>>16); }               // RNE

DEV void async16(const u16* g, u16* l){
  __builtin_amdgcn_global_load_lds((__attribute__((address_space(1))) void*)(uintptr_t)g,
                                   (__attribute__((address_space(3))) void*)l, 16, 0, 0);
}

// gelu tanh-approx via sigmoid identity: 0.5x(1+tanh(u)) = x * 1/(1+exp(-2u)),
// -2u = x*(-1.5957691216 - 0.071354816*x^2). ~8 VALU ops, correct limits both signs.
DEV float gelu_fast(float x){
  float x2 = x*x;
  float t  = __builtin_fmaf(x2, -0.071354816f, -1.5957691216f);
  float e  = __expf(x*t);
  return __fdividef(x, 1.f + e);
}

// XCD-aware bijective block swizzle (requires nwg%8==0 — all GEMM grids here satisfy).
DEV int2 xcd_swz(){
  const int gx  = gridDim.x;
  const int ord = blockIdx.y*gx + blockIdx.x;
  const int nwg = gx*gridDim.y;
  const int wg  = (ord&7)*(nwg>>3) + (ord>>3);
  int2 r; r.x = wg % gx; r.y = wg / gx; return r;
}

// ---------------- weight fp32 -> bf16 pack ----------------
struct WDesc { const float* src[14]; int off[14]; };
__global__ __launch_bounds__(256) void convw_kernel(WDesc d, u16* __restrict__ dst){
  int i = blockIdx.x*256 + threadIdx.x;
  int s = 0;
  #pragma unroll
  for(int j=1;j<14;j++) if(i >= d.off[j]) s = j;
  dst[i] = f2bf(d.src[s][i - d.off[s]]);
}

// ---------------- LayerNorm (C=512), fp32 in -> bf16 out ----------------
DEV float wsum64(float s){
  s += __shfl_xor(s,1,64);  s += __shfl_xor(s,2,64);  s += __shfl_xor(s,4,64);
  s += __shfl_xor(s,8,64);  s += __shfl_xor(s,16,64); s += __shfl_xor(s,32,64);
  return s;
}
DEV void ln_row(const float* xrow, const float* g, const float* bta, u16* orow, int lane){
  const float4* xr = (const float4*)xrow + lane*2;
  float4 a = xr[0], c = xr[1];
  float s = a.x+a.y+a.z+a.w + c.x+c.y+c.z+c.w;
  float mean = wsum64(s) * (1.f/512.f);
  float d0=a.x-mean,d1=a.y-mean,d2=a.z-mean,d3=a.w-mean;
  float d4=c.x-mean,d5=c.y-mean,d6=c.z-mean,d7=c.w-mean;
  float sv = d0*d0+d1*d1+d2*d2+d3*d3+d4*d4+d5*d5+d6*d6+d7*d7;
  float rstd = rsqrtf(wsum64(sv)*(1.f/512.f) + 1e-5f);
  const float4* gr = (const float4*)g   + lane*2;
  const float4* br = (const float4*)bta + lane*2;
  float4 g0=gr[0], g1=gr[1], b0=br[0], b1=br[1];
  bh8 o;
  o[0]=(short)f2bf(d0*rstd*g0.x+b0.x); o[1]=(short)f2bf(d1*rstd*g0.y+b0.y);
  o[2]=(short)f2bf(d2*rstd*g0.z+b0.z); o[3]=(short)f2bf(d3*rstd*g0.w+b0.w);
  o[4]=(short)f2bf(d4*rstd*g1.x+b1.x); o[5]=(short)f2bf(d5*rstd*g1.y+b1.y);
  o[6]=(short)f2bf(d6*rstd*g1.z+b1.z); o[7]=(short)f2bf(d7*rstd*g1.w+b1.w);
  *(bh8*)(orow + lane*8) = o;
}
__global__ __launch_bounds__(256) void ln_kernel(const float* __restrict__ x,
    const float* __restrict__ g, const float* __restrict__ bta, u16* __restrict__ out){
  int row  = blockIdx.x*4 + (threadIdx.x>>6);
  ln_row(x + (size_t)row*512, g, bta, out + (size_t)row*512, threadIdx.x&63);
}
__global__ __launch_bounds__(256) void lny_kernel(const float* __restrict__ ys,
    const float* __restrict__ g2, const float* __restrict__ b2, u16* __restrict__ out){
  int row  = blockIdx.x*4 + (threadIdx.x>>6);
  int i = row>>14;
  ln_row(ys + (size_t)row*512, g2 + i*512, b2 + i*512, out + (size_t)row*512, threadIdx.x&63);
}

// ---- shared GEMM K-loop pieces: 128x128 tile, BK=32, swizzled LDS (conflict-free).
// C/D layout: out_row = quad*4+r (within 16), out_col = l15.
#define GEMM_STAGE(Ab, Wb, K, kk, buf)                                               \
    async16(Ab + (size_t)srow*(K)      + (kk) + scol, &lsA[buf][(w*32   )*32]);      \
    async16(Ab + (size_t)(srow+16)*(K) + (kk) + scol, &lsA[buf][(w*32+16)*32]);      \
    async16(Wb + (size_t)srow*(K)      + (kk) + scol, &lsB[buf][(w*32   )*32]);      \
    async16(Wb + (size_t)(srow+16)*(K) + (kk) + scol, &lsB[buf][(w*32+16)*32]);

#define GEMM_FRAG_MFMA(cur)                                                          \
    bh8 af[4], bfx[4];                                                               \
    _Pragma("unroll")                                                                \
    for(int t=0;t<4;t++){                                                            \
      af[t]  = *(const bh8*)&lsA[cur][(wm*64+t*16+l15)*32 + rsw*8];                  \
      bfx[t] = *(const bh8*)&lsB[cur][(wn*64+t*16+l15)*32 + rsw*8];                  \
    }                                                                                \
    _Pragma("unroll")                                                                \
    for(int mt=0;mt<4;mt++)                                                          \
      _Pragma("unroll")                                                              \
      for(int nt=0;nt<4;nt++)                                                        \
        acc[mt][nt] = __builtin_amdgcn_mfma_f32_16x16x32_bf16(af[mt], bfx[nt], acc[mt][nt], 0,0,0);

// Counted-vmcnt raw-barrier loop (best for EPI3 / qkv shapes, R8-proven).
#define GEMM_KLOOP_CNT(Ab, Wb, K) {                                                  \
  const int srow = w*32 + (lane>>2);                                                 \
  const int scol = (((lane&3) ^ ((srow>>1)&3)) * 8);                                 \
  const int rsw  = ((l15>>1)&3) ^ quad;                                              \
  GEMM_STAGE(Ab, Wb, K, 0, 0)                                                        \
  const int NS = (K)>>5;                                                             \
  for(int j=0;j<NS;j++){                                                             \
    const int cur = j&1;                                                             \
    if(j+1<NS){                                                                      \
      GEMM_STAGE(Ab, Wb, K, (j+1)*32, cur^1)                                         \
      asm volatile("s_waitcnt vmcnt(4)" ::: "memory");                               \
    } else {                                                                         \
      asm volatile("s_waitcnt vmcnt(0)" ::: "memory");                               \
    }                                                                                \
    __builtin_amdgcn_s_barrier();                                                    \
    GEMM_FRAG_MFMA(cur)                                                              \
    __builtin_amdgcn_s_barrier();                                                    \
  } }

// Single-__syncthreads dbuf loop (best for EPI2 up-proj, R7/R9-proven).
#define GEMM_KLOOP_SYNC(Ab, Wb, K) {                                                 \
  const int srow = w*32 + (lane>>2);                                                 \
  const int scol = (((lane&3) ^ ((srow>>1)&3)) * 8);                                 \
  const int rsw  = ((l15>>1)&3) ^ quad;                                              \
  GEMM_STAGE(Ab, Wb, K, 0, 0)                                                        \
  __syncthreads();                                                                   \
  for(int k0=0;k0<K;k0+=32){                                                         \
    const int cur = (k0>>5)&1;                                                       \
    if(k0+32 < K){ GEMM_STAGE(Ab, Wb, K, k0+32, cur^1) }                             \
    GEMM_FRAG_MFMA(cur)                                                              \
    __syncthreads();                                                                 \
  } }

// Softmax + optional colsum epilogue (shared by q/k projections).
#define SOFTMAX_EPI(outp, ksp, rowbase)                                              \
    float ksacc[4] = {0.f,0.f,0.f,0.f};                                              \
    _Pragma("unroll")                                                                \
    for(int mt=0;mt<4;mt++)                                                          \
      _Pragma("unroll")                                                              \
      for(int r=0;r<4;r++){                                                          \
        float v0=acc[mt][0][r]+bcol[0], v1=acc[mt][1][r]+bcol[1];                    \
        float v2=acc[mt][2][r]+bcol[2], v3=acc[mt][3][r]+bcol[3];                    \
        float mx = fmaxf(fmaxf(v0,v1),fmaxf(v2,v3));                                 \
        mx = fmaxf(mx,__shfl_xor(mx,1,64)); mx = fmaxf(mx,__shfl_xor(mx,2,64));      \
        mx = fmaxf(mx,__shfl_xor(mx,4,64)); mx = fmaxf(mx,__shfl_xor(mx,8,64));      \
        float e0=__expf(v0-mx), e1=__expf(v1-mx), e2=__expf(v2-mx), e3=__expf(v3-mx);\
        float s = e0+e1+e2+e3;                                                       \
        s += __shfl_xor(s,1,64); s += __shfl_xor(s,2,64);                            \
        s += __shfl_xor(s,4,64); s += __shfl_xor(s,8,64);                            \
        float inv = __fdividef(1.f, s);                                              \
        e0*=inv; e1*=inv; e2*=inv; e3*=inv;                                          \
        ksacc[0]+=e0; ksacc[1]+=e1; ksacc[2]+=e2; ksacc[3]+=e3;                      \
        int row = (rowbase) + wm*64 + mt*16 + quad*4 + r;                            \
        size_t rb = (size_t)row*512;                                                 \
        outp[rb+colw+ 0+l15]=f2bf(e0); outp[rb+colw+16+l15]=f2bf(e1);                \
        outp[rb+colw+32+l15]=f2bf(e2); outp[rb+colw+48+l15]=f2bf(e3);                \
      }                                                                              \
    if(ksp){                                                                         \
      _Pragma("unroll")                                                              \
      for(int nt=0;nt<4;nt++){                                                       \
        float s = ksacc[nt];                                                         \
        s += __shfl_xor(s,16,64); s += __shfl_xor(s,32,64);                          \
        if(quad==0) atomicAdd(&ksp[colw + nt*16 + l15], s);                          \
      }                                                                              \
    }

// ---------------- SA fused q/k/v projection (3 subs, CNT loop) ----------------
struct SubD { const float* bias; u16* out; float* ksum; int mode; };
struct Subs3 { SubD s[3]; };
__global__ __launch_bounds__(256) void gemm_qkv(const u16* __restrict__ A,
    const u16* __restrict__ W, Subs3 subs, int K){
  __shared__ __align__(16) u16 lsA[2][128*32];
  __shared__ __align__(16) u16 lsB[2][128*32];
  const int tid = threadIdx.x, lane = tid&63, w = tid>>6;
  const int quad = lane>>4, l15 = lane&15;
  const int2 swz = xcd_swz();
  const int bn = swz.x, bm = swz.y;
  const int wm = w&1, wn = w>>1;
  fx4 acc[4][4];
  #pragma unroll
  for(int i=0;i<4;i++)
    #pragma unroll
    for(int j=0;j<4;j++) acc[i][j] = (fx4){0.f,0.f,0.f,0.f};
  const u16* Ab = A + (size_t)bm*128*K;
  const u16* Wb = W + (size_t)bn*128*K;
  GEMM_KLOOP_CNT(Ab, Wb, K)
  const SubD sub = subs.s[bn>>2];
  const int colw = (bn&3)*128 + wn*64;
  float bcol[4];
  #pragma unroll
  for(int nt=0;nt<4;nt++) bcol[nt] = sub.bias[colw + nt*16 + l15];

  if(sub.mode==1){
    float* ksp = sub.ksum ? (sub.ksum + ((bm&127)>>5)*512) : nullptr;
    u16* outp = sub.out;
    SOFTMAX_EPI(outp, ksp, bm*128)
  } else {
    #pragma unroll
    for(int mt=0;mt<4;mt++)
      #pragma unroll
      for(int r=0;r<4;r++){
        int row = bm*128 + wm*64 + mt*16 + quad*4 + r;
        size_t rb = (size_t)row*512;
        #pragma unroll
        for(int nt=0;nt<4;nt++)
          sub.out[rb + colw + nt*16 + l15] = f2bf(acc[mt][nt][r] + bcol[nt]);
      }
  }
}

// ---------------- CA merged q + k/v projection (grid 8 x 384, K=512) ----------------
// bm<128: q-proj from Aq (bn<4 only; bn>=4 blocks exit before any barrier).
// bm>=128: kv-proj from Akv (32768 rows, 2 input sets), bn 0-3 -> K, 4-7 -> V.
__global__ __launch_bounds__(256) void gemm_ca(const u16* __restrict__ Aq,
    const u16* __restrict__ Akv, const u16* __restrict__ W,
    const float* __restrict__ bq, const float* __restrict__ bk,
    const float* __restrict__ bv, u16* __restrict__ qb, u16* __restrict__ kb,
    u16* __restrict__ vb, float* __restrict__ ksum){
  __shared__ __align__(16) u16 lsA[2][128*32];
  __shared__ __align__(16) u16 lsB[2][128*32];
  const int tid = threadIdx.x, lane = tid&63, w = tid>>6;
  const int quad = lane>>4, l15 = lane&15;
  const int2 swz = xcd_swz();
  const int bn = swz.x, bm = swz.y;
  const int wm = w&1, wn = w>>1;
  const int isQ = (bm < 128);
  if(isQ && bn >= 4) return;                 // block-uniform exit, precedes barriers
  const u16 *Ab, *Wb; const float* bias; u16* outp; float* ksp; int mode, rowbase;
  if(isQ){
    Ab = Aq + (size_t)bm*128*512;
    Wb = W  + (size_t)bn*128*512;
    bias = bq; outp = qb; ksp = nullptr; mode = 1; rowbase = bm*128;
  } else {
    const int kbm = bm - 128, i = kbm>>7;
    Ab = Akv + (size_t)kbm*128*512;
    Wb = W + 262144 + (size_t)i*524288 + (size_t)bn*128*512;
    rowbase = kbm*128;
    if((bn>>2)==0){ bias = bk + i*512; outp = kb;
                    ksp = ksum + i*2048 + ((kbm&127)>>5)*512; mode = 1; }
    else          { bias = bv + i*512; outp = vb; ksp = nullptr; mode = 0; }
  }
  fx4 acc[4][4];
  #pragma unroll
  for(int i=0;i<4;i++)
    #pragma unroll
    for(int j=0;j<4;j++) acc[i][j] = (fx4){0.f,0.f,0.f,0.f};
  GEMM_KLOOP_CNT(Ab, Wb, 512)
  const int colw = (bn&3)*128 + wn*64;
  float bcol[4];
  #pragma unroll
  for(int nt=0;nt<4;nt++) bcol[nt] = bias[colw + nt*16 + l15];
  if(mode==1){
    SOFTMAX_EPI(outp, ksp, rowbase)
  } else {
    #pragma unroll
    for(int mt=0;mt<4;mt++)
      #pragma unroll
      for(int r=0;r<4;r++){
        int row = rowbase + wm*64 + mt*16 + quad*4 + r;
        size_t rb = (size_t)row*512;
        #pragma unroll
        for(int nt=0;nt<4;nt++)
          outp[rb + colw + nt*16 + l15] = f2bf(acc[mt][nt][r] + bcol[nt]);
      }
  }
}

// ---------------- FFN up-proj: C = A*W^T + bias -> gelu -> bf16 (SYNC loop) ----------------
__global__ __launch_bounds__(256) void gemm_up(const u16* __restrict__ A,
    const u16* __restrict__ W, const float* __restrict__ bias,
    u16* __restrict__ out, int N, int K){
  __shared__ __align__(16) u16 lsA[2][128*32];
  __shared__ __align__(16) u16 lsB[2][128*32];
  const int tid = threadIdx.x, lane = tid&63, w = tid>>6;
  const int quad = lane>>4, l15 = lane&15;
  const int2 swz = xcd_swz();
  const int bn = swz.x, bm = swz.y;
  const int wm = w&1, wn = w>>1;
  fx4 acc[4][4];
  #pragma unroll
  for(int i=0;i<4;i++)
    #pragma unroll
    for(int j=0;j<4;j++) acc[i][j] = (fx4){0.f,0.f,0.f,0.f};
  const u16* Ab = A + (size_t)bm*128*K;
  const u16* Wb = W + (size_t)bn*128*K;
  GEMM_KLOOP_SYNC(Ab, Wb, K)
  const int colbase = bn*128 + wn*64;
  float bcol[4];
  #pragma unroll
  for(int nt=0;nt<4;nt++) bcol[nt] = bias[colbase + nt*16 + l15];
  #pragma unroll
  for(int mt=0;mt<4;mt++)
    #pragma unroll
    for(int r=0;r<4;r++){
      int row = bm*128 + wm*64 + mt*16 + quad*4 + r;
      size_t rb = (size_t)row*N;
      #pragma unroll
      for(int nt=0;nt<4;nt++)
        out[rb + colbase + nt*16 + l15] = f2bf(gelu_fast(acc[mt][nt][r] + bcol[nt]));
    }
}

// -------- down/out-proj: C = A*W^T + bias + res -> fp32 (CNT loop) --------
__global__ __launch_bounds__(256) void gemm_dn(const u16* __restrict__ A,
    const u16* __restrict__ W, const float* __restrict__ bias,
    const float* __restrict__ res, float* __restrict__ out, int N, int K){
  __shared__ __align__(16) u16 lsA[2][128*32];
  __shared__ __align__(16) u16 lsB[2][128*32];
  const int tid = threadIdx.x, lane = tid&63, w = tid>>6;
  const int quad = lane>>4, l15 = lane&15;
  const int2 swz = xcd_swz();
  const int bn = swz.x, bm = swz.y;
  const int wm = w&1, wn = w>>1;
  fx4 acc[4][4];
  #pragma unroll
  for(int i=0;i<4;i++)
    #pragma unroll
    for(int j=0;j<4;j++) acc[i][j] = (fx4){0.f,0.f,0.f,0.f};
  const u16* Ab = A + (size_t)bm*128*K;
  const u16* Wb = W + (size_t)bn*128*K;
  GEMM_KLOOP_CNT(Ab, Wb, K)
  const int colbase = bn*128 + wn*64;
  float bcol[4];
  #pragma unroll
  for(int nt=0;nt<4;nt++) bcol[nt] = bias[colbase + nt*16 + l15];
  #pragma unroll
  for(int mt=0;mt<4;mt++)
    #pragma unroll
    for(int r=0;r<4;r++){
      int row = bm*128 + wm*64 + mt*16 + quad*4 + r;
      size_t rb = (size_t)row*N;
      #pragma unroll
      for(int nt=0;nt<4;nt++){
        int col = colbase + nt*16 + l15;
        out[rb+col] = res[rb+col] + acc[mt][nt][r] + bcol[nt];
      }
    }
}

// ---------------- ctx[i,b,h][d1][d2] = sum_t k[t][d1] v[t][d2] (MFMA over t) ----------------
__global__ __launch_bounds__(256) void ctx_kernel(const u16* __restrict__ kb,
    const u16* __restrict__ vb, float* __restrict__ ctx, size_t kstride){
  __shared__ __align__(16) u16 lk[64*72];  // transposed [d][t], stride 72
  __shared__ __align__(16) u16 lv[64*72];
  const int tid=threadIdx.x, lane=tid&63, w=tid>>6, quad=lane>>4, l15=lane&15;
  const int bh2 = blockIdx.x, i = bh2>>5, h = bh2&7, b = (bh2>>3)&3;
  const u16* kbase = kb + (size_t)i*kstride;
  const u16* vbase = vb + (size_t)i*kstride;
  const size_t rowbase = (size_t)b*4096 + (size_t)blockIdx.y*512;
  const int mt0=(w&1)*32, nt0=(w>>1)*32;
  fx4 acc[2][2];
  #pragma unroll
  for(int x=0;x<2;x++)
    #pragma unroll
    for(int j=0;j<2;j++) acc[x][j] = (fx4){0.f,0.f,0.f,0.f};
  const int tl = tid>>2, part = tid&3;
  for(int it=0; it<8; it++){
    __syncthreads();
    {
      size_t gro = (rowbase + it*64 + tl)*512 + h*64 + part*16;
      bh8 k0 = *(const bh8*)(kbase + gro); bh8 k1 = *(const bh8*)(kbase + gro + 8);
      bh8 v0 = *(const bh8*)(vbase + gro); bh8 v1 = *(const bh8*)(vbase + gro + 8);
      #pragma unroll
      for(int j=0;j<8;j++){
        lk[(part*16+j  )*72 + tl] = (u16)k0[j];
        lk[(part*16+8+j)*72 + tl] = (u16)k1[j];
        lv[(part*16+j  )*72 + tl] = (u16)v0[j];
        lv[(part*16+8+j)*72 + tl] = (u16)v1[j];
      }
    }
    __syncthreads();
    #pragma unroll
    for(int ks=0;ks<2;ks++){
      bh8 a0 = *(const bh8*)&lk[(mt0    +l15)*72 + ks*32 + quad*8];
      bh8 a1 = *(const bh8*)&lk[(mt0+16 +l15)*72 + ks*32 + quad*8];
      bh8 b0 = *(const bh8*)&lv[(nt0    +l15)*72 + ks*32 + quad*8];
      bh8 b1 = *(const bh8*)&lv[(nt0+16 +l15)*72 + ks*32 + quad*8];
      acc[0][0] = __builtin_amdgcn_mfma_f32_16x16x32_bf16(a0,b0,acc[0][0],0,0,0);
      acc[0][1] = __builtin_amdgcn_mfma_f32_16x16x32_bf16(a0,b1,acc[0][1],0,0,0);
      acc[1][0] = __builtin_amdgcn_mfma_f32_16x16x32_bf16(a1,b0,acc[1][0],0,0,0);
      acc[1][1] = __builtin_amdgcn_mfma_f32_16x16x32_bf16(a1,b1,acc[1][1],0,0,0);
    }
  }
  float* cb = ctx + (size_t)bh2*4096;
  #pragma unroll
  for(int mi=0;mi<2;mi++)
    #pragma unroll
    for(int ni=0;ni<2;ni++)
      #pragma unroll
      for(int r=0;r<4;r++){
        int d1 = mt0 + mi*16 + quad*4 + r;
        int d2 = nt0 + ni*16 + l15;
        atomicAdd(&cb[d1*64 + d2], acc[mi][ni][r]);
      }
}

// ------- out = q + sum_i (q @ ctx_i) * Dinv_i, Dinv fused (quad-shuffle over q frags) -------
template<int NIN>
__global__ __launch_bounds__(256) void apply_kernel(const u16* __restrict__ q,
    const float* __restrict__ ctx, const float* __restrict__ ksum, float eps,
    u16* __restrict__ out){
  __shared__ __align__(16) u16 lctx[(NIN+1)*64*72];
  const int tid=threadIdx.x, lane=tid&63, w=tid>>6, quad=lane>>4, l15=lane&15;
  const int bh = blockIdx.x, b=bh>>3, h=bh&7;
  {
    int base = tid*16;
    int d1 = base>>6, d2b = base&63;
    #pragma unroll
    for(int s=0;s<=NIN;s++){
      u16* dst = &lctx[s*64*72];
      if(s<NIN){
        const float* sp = ctx + ((size_t)s*32 + bh)*4096 + base;
        #pragma unroll
        for(int j=0;j<16;j++) dst[(d2b+j)*72 + d1] = f2bf(sp[j]);
      } else {
        #pragma unroll
        for(int j=0;j<16;j++) dst[(d2b+j)*72 + d1] = ((d2b+j)==d1) ? (u16)0x3f80 : (u16)0;
      }
    }
  }
  float kslo[NIN][8], kshi[NIN][8];
  #pragma unroll
  for(int s=0;s<NIN;s++){
    const float* ks = ksum + s*2048 + b*512 + h*64;
    #pragma unroll
    for(int j=0;j<8;j++){ kslo[s][j] = ks[quad*8+j]; kshi[s][j] = ks[32+quad*8+j]; }
  }
  __syncthreads();
  bh8 bfr[NIN+1][4][2];
  #pragma unroll
  for(int s=0;s<=NIN;s++)
    #pragma unroll
    for(int nt=0;nt<4;nt++)
      #pragma unroll
      for(int ks=0;ks<2;ks++)
        bfr[s][nt][ks] = *(const bh8*)&lctx[s*64*72 + (nt*16+l15)*72 + ks*32 + quad*8];
  const size_t tb0 = (size_t)b*4096 + (size_t)blockIdx.y*256 + w*64;
  for(int g=0;g<4;g++){
    size_t tb = tb0 + g*16;
    const u16* qr = q + (tb + l15)*512 + h*64;
    bh8 a0 = *(const bh8*)(qr + quad*8);
    bh8 a1 = *(const bh8*)(qr + 32 + quad*8);
    float dv[NIN][4];
    #pragma unroll
    for(int s=0;s<NIN;s++){
      float part = 0.f;
      #pragma unroll
      for(int j=0;j<8;j++)
        part += bf2f((u16)a0[j])*kslo[s][j] + bf2f((u16)a1[j])*kshi[s][j];
      part += __shfl_xor(part,16,64); part += __shfl_xor(part,32,64);
      #pragma unroll
      for(int r=0;r<4;r++)
        dv[s][r] = __fdividef(1.f, __shfl(part, quad*4+r, 64) + eps);
    }
    fx4 outv[4];
    #pragma unroll
    for(int nt=0;nt<4;nt++) outv[nt] = (fx4){0.f,0.f,0.f,0.f};
    #pragma unroll
    for(int s=0;s<=NIN;s++){
      fx4 c[4];
      #pragma unroll
      for(int nt=0;nt<4;nt++){
        c[nt] = (fx4){0.f,0.f,0.f,0.f};
        c[nt] = __builtin_amdgcn_mfma_f32_16x16x32_bf16(a0, bfr[s][nt][0], c[nt], 0,0,0);
        c[nt] = __builtin_amdgcn_mfma_f32_16x16x32_bf16(a1, bfr[s][nt][1], c[nt], 0,0,0);
      }
      #pragma unroll
      for(int nt=0;nt<4;nt++)
        #pragma unroll
        for(int r=0;r<4;r++) outv[nt][r] += c[nt][r]*((s==NIN)?1.f:dv[s][r]);
    }
    #pragma unroll
    for(int nt=0;nt<4;nt++)
      #pragma unroll
      for(int r=0;r<4;r++)
        out[(tb+quad*4+r)*512 + h*64 + nt*16 + l15] = f2bf(outv[nt][r]);
  }
}

// =========================================================================
extern "C" void kernel_launch(void* const* d_in, const int* in_sizes, int n_in,
                              void* d_out, int out_size, void* d_ws, size_t ws_size,
                              hipStream_t stream){
  const float* x_in =(const float*)d_in[0];
  const float* ys   =(const float*)d_in[1];
  const float* ln1g =(const float*)d_in[2],  *ln1b=(const float*)d_in[3];
  const float* ln2g =(const float*)d_in[4],  *ln2b=(const float*)d_in[5];
  const float* ln3g =(const float*)d_in[6],  *ln3b=(const float*)d_in[7];
  const float* ln4g =(const float*)d_in[8],  *ln4b=(const float*)d_in[9];
  const float* ln5g =(const float*)d_in[10], *ln5b=(const float*)d_in[11];
  const float* ca_wq=(const float*)d_in[12], *ca_bq=(const float*)d_in[13];
  const float* ca_wk=(const float*)d_in[14], *ca_bk=(const float*)d_in[15];
  const float* ca_wv=(const float*)d_in[16], *ca_bv=(const float*)d_in[17];
  const float* ca_wo=(const float*)d_in[18], *ca_bo=(const float*)d_in[19];
  const float* sa_wq=(const float*)d_in[20], *sa_bq=(const float*)d_in[21];
  const float* sa_wk=(const float*)d_in[22], *sa_bk=(const float*)d_in[23];
  const float* sa_wv=(const float*)d_in[24], *sa_bv=(const float*)d_in[25];
  const float* sa_wo=(const float*)d_in[26], *sa_bo=(const float*)d_in[27];
  const float* f1w1 =(const float*)d_in[28], *f1b1=(const float*)d_in[29];
  const float* f1w2 =(const float*)d_in[30], *f1b2=(const float*)d_in[31];
  const float* f2w1 =(const float*)d_in[32], *f2b1=(const float*)d_in[33];
  const float* f2w2 =(const float*)d_in[34], *f2b2=(const float*)d_in[35];

  char* p = (char*)d_ws;
  u16*   WBF = (u16*)p;    p += 13631488;   // bf16 weights
  float* XW  = (float*)p;  p += 33554432;   // residual stream fp32 [16384,512]
  u16*   XN2 = (u16*)p;    p += 33554432;   // LN out, up to 2x16384 rows
  u16*   QB  = (u16*)p;    p += 16777216;
  u16*   R1  = (u16*)p;    p += 67108864;   // FFN hidden [16384,2048] OR stacked KB2|VB2
  u16*   OUTB= (u16*)p;    p += 16777216;   // attention output (also stages CA x-LN)
  float* SM  = (float*)p;  p += 1597440;    // ctx + ksum (zeroed)
  u16*   XN  = XN2;
  u16*   KB2 = R1;
  u16*   VB2 = R1 + 16777216;
  u16*   HB  = R1;
  float* CTXC = SM;                          // [2][32][4096]
  float* CTXS = SM + 262144;                 // [32][4096]
  float* KSC  = SM + 393216;                 // [2][4][512]
  float* KSS  = SM + 397312;                 // [4][512]

  WDesc wd;
  const float* wsrc[14] = {ca_wq, ca_wk, ca_wv, ca_wk+262144, ca_wv+262144, ca_wo,
                           sa_wq, sa_wk, sa_wv, sa_wo, f1w1, f1w2, f2w1, f2w2};
  const int    woff[14] = {0, 262144, 524288, 786432, 1048576, 1310720,
                           1572864, 1835008, 2097152, 2359296,
                           2621440, 3670016, 4718592, 5767168};
  for(int i=0;i<14;i++){ wd.src[i]=wsrc[i]; wd.off[i]=woff[i]; }
  convw_kernel<<<26624,256,0,stream>>>(wd, WBF);
  hipMemsetAsync(SM, 0, 399360*sizeof(float), stream);

  // ---- cross attention ----
  ln_kernel<<<4096,256,0,stream>>>(x_in, ln1g, ln1b, OUTB);   // x-LN staged in OUTB
  lny_kernel<<<8192,256,0,stream>>>(ys, ln2g, ln2b, XN2);     // both ys LNs
  gemm_ca<<<dim3(8,384),256,0,stream>>>(OUTB, XN2, WBF, ca_bq, ca_bk, ca_bv,
                                        QB, KB2, VB2, KSC);
  ctx_kernel<<<dim3(64,8),256,0,stream>>>(KB2, VB2, CTXC, (size_t)16384*512);
  apply_kernel<2><<<dim3(32,16),256,0,stream>>>(QB, CTXC, KSC, 1e-8f, OUTB);
  gemm_dn<<<dim3(4,128),256,0,stream>>>(OUTB, WBF+1310720, ca_bo, x_in, XW, 512, 512);

  // ---- FFN 1 ----
  ln_kernel<<<4096,256,0,stream>>>(XW, ln3g, ln3b, XN);
  gemm_up<<<dim3(16,128),256,0,stream>>>(XN, WBF+2621440, f1b1, HB, 2048, 512);
  gemm_dn<<<dim3(4,128),256,0,stream>>>(HB, WBF+3670016, f1b2, XW, XW, 512, 2048);

  // ---- linear self attention ----
  ln_kernel<<<4096,256,0,stream>>>(XW, ln4g, ln4b, XN);
  { Subs3 s = {{ {sa_bq, QB, nullptr, 1}, {sa_bk, KB2, KSS, 1}, {sa_bv, VB2, nullptr, 0} }};
    gemm_qkv<<<dim3(12,128),256,0,stream>>>(XN, WBF+1572864, s, 512); }
  ctx_kernel<<<dim3(32,8),256,0,stream>>>(KB2, VB2, CTXS, 0);
  apply_kernel<1><<<dim3(32,16),256,0,stream>>>(QB, CTXS, KSS, 0.f, OUTB);
  gemm_dn<<<dim3(4,128),256,0,stream>>>(OUTB, WBF+2359296, sa_bo, XW, XW, 512, 512);

  // ---- FFN 2 ----
  ln_kernel<<<4096,256,0,stream>>>(XW, ln5g, ln5b, XN);
  gemm_up<<<dim3(16,128),256,0,stream>>>(XN, WBF+4718592, f2b1, HB, 2048, 512);
  gemm_dn<<<dim3(4,128),256,0,stream>>>(HB, WBF+5767168, f2b2, XW, (float*)d_out, 512, 2048);
}

// Round 5
// 709.696 us; speedup vs baseline: 1.0076x; 1.0076x over previous
//
// CrossAttentionBlock_56813827392085 — fused transformer block, bf16 MFMA internals. R11:
//  = R9 dispatch structure (CA merge REVERTED — R10's gemm_ca hit VGPR92/occ16%, 94.9us)
//  + BN=64 tiles for all grid-starved N=512 GEMMs:
//    gemm_dn64 (out/down-proj, CNT loop) and gemm_q64 (CA q-proj, softmax epi):
//    grid (8,128)=1024 blocks = 4 blocks/CU (was 512 = 2/CU, grid-limited at occupancy
//    20% -> MfmaUtil 20%, latency-bound). Wave layout 4x1 (32 rows x 64 cols each) keeps
//    the per-head softmax reduction within one wave. LDS 24KB (cap 6/CU).
//  Kept: CNT counted-vmcnt loop (qkv/dn), SYNC loop (up-proj), sigmoid gelu, XCD swizzle,
//  de-templated gemm_up/gemm_dn, fused dinv / colsum-softmax epilogues.
#include <hip/hip_runtime.h>
#include <hip/hip_bf16.h>
#include <math.h>
#include <stdint.h>

typedef unsigned short u16;
typedef __attribute__((ext_vector_type(8))) short bh8;
typedef __attribute__((ext_vector_type(4))) float fx4;

#define DEV static __device__ __forceinline__

DEV float bf2f(u16 u){ union{unsigned u; float f;} v; v.u = ((unsigned)u)<<16; return v.f; }
DEV u16 f2bf(float f){ union{float f; unsigned u;} v; v.f = f;
  return (u16)((v.u + 0x7fffu + ((v.u>>16)&1u))>>16); }               // RNE

DEV void async16(const u16* g, u16* l){
  __builtin_amdgcn_global_load_lds((__attribute__((address_space(1))) void*)(uintptr_t)g,
                                   (__attribute__((address_space(3))) void*)l, 16, 0, 0);
}

// gelu tanh-approx via sigmoid identity: x * 1/(1+exp(x*(-1.59577 - 0.0713548*x^2)))
DEV float gelu_fast(float x){
  float x2 = x*x;
  float t  = __builtin_fmaf(x2, -0.071354816f, -1.5957691216f);
  float e  = __expf(x*t);
  return __fdividef(x, 1.f + e);
}

// XCD-aware bijective block swizzle (requires nwg%8==0 — all GEMM grids here satisfy).
DEV int2 xcd_swz(){
  const int gx  = gridDim.x;
  const int ord = blockIdx.y*gx + blockIdx.x;
  const int nwg = gx*gridDim.y;
  const int wg  = (ord&7)*(nwg>>3) + (ord>>3);
  int2 r; r.x = wg % gx; r.y = wg / gx; return r;
}

// ---------------- weight fp32 -> bf16 pack ----------------
struct WDesc { const float* src[14]; int off[14]; };
__global__ __launch_bounds__(256) void convw_kernel(WDesc d, u16* __restrict__ dst){
  int i = blockIdx.x*256 + threadIdx.x;
  int s = 0;
  #pragma unroll
  for(int j=1;j<14;j++) if(i >= d.off[j]) s = j;
  dst[i] = f2bf(d.src[s][i - d.off[s]]);
}

// ---------------- LayerNorm (C=512), fp32 in -> bf16 out ----------------
DEV float wsum64(float s){
  s += __shfl_xor(s,1,64);  s += __shfl_xor(s,2,64);  s += __shfl_xor(s,4,64);
  s += __shfl_xor(s,8,64);  s += __shfl_xor(s,16,64); s += __shfl_xor(s,32,64);
  return s;
}
DEV void ln_row(const float* xrow, const float* g, const float* bta, u16* orow, int lane){
  const float4* xr = (const float4*)xrow + lane*2;
  float4 a = xr[0], c = xr[1];
  float s = a.x+a.y+a.z+a.w + c.x+c.y+c.z+c.w;
  float mean = wsum64(s) * (1.f/512.f);
  float d0=a.x-mean,d1=a.y-mean,d2=a.z-mean,d3=a.w-mean;
  float d4=c.x-mean,d5=c.y-mean,d6=c.z-mean,d7=c.w-mean;
  float sv = d0*d0+d1*d1+d2*d2+d3*d3+d4*d4+d5*d5+d6*d6+d7*d7;
  float rstd = rsqrtf(wsum64(sv)*(1.f/512.f) + 1e-5f);
  const float4* gr = (const float4*)g   + lane*2;
  const float4* br = (const float4*)bta + lane*2;
  float4 g0=gr[0], g1=gr[1], b0=br[0], b1=br[1];
  bh8 o;
  o[0]=(short)f2bf(d0*rstd*g0.x+b0.x); o[1]=(short)f2bf(d1*rstd*g0.y+b0.y);
  o[2]=(short)f2bf(d2*rstd*g0.z+b0.z); o[3]=(short)f2bf(d3*rstd*g0.w+b0.w);
  o[4]=(short)f2bf(d4*rstd*g1.x+b1.x); o[5]=(short)f2bf(d5*rstd*g1.y+b1.y);
  o[6]=(short)f2bf(d6*rstd*g1.z+b1.z); o[7]=(short)f2bf(d7*rstd*g1.w+b1.w);
  *(bh8*)(orow + lane*8) = o;
}
__global__ __launch_bounds__(256) void ln_kernel(const float* __restrict__ x,
    const float* __restrict__ g, const float* __restrict__ bta, u16* __restrict__ out){
  int row  = blockIdx.x*4 + (threadIdx.x>>6);
  ln_row(x + (size_t)row*512, g, bta, out + (size_t)row*512, threadIdx.x&63);
}
__global__ __launch_bounds__(256) void lny_kernel(const float* __restrict__ ys,
    const float* __restrict__ g2, const float* __restrict__ b2, u16* __restrict__ out){
  int row  = blockIdx.x*4 + (threadIdx.x>>6);
  int i = row>>14;
  ln_row(ys + (size_t)row*512, g2 + i*512, b2 + i*512, out + (size_t)row*512, threadIdx.x&63);
}

// ---- BN=128 K-loop pieces: 128x128 tile, BK=32, swizzled LDS (conflict-free). ----
// C/D layout: out_row = quad*4+r (within 16), out_col = l15.
#define GEMM_STAGE(Ab, Wb, K, kk, buf)                                               \
    async16(Ab + (size_t)srow*(K)      + (kk) + scol, &lsA[buf][(w*32   )*32]);      \
    async16(Ab + (size_t)(srow+16)*(K) + (kk) + scol, &lsA[buf][(w*32+16)*32]);      \
    async16(Wb + (size_t)srow*(K)      + (kk) + scol, &lsB[buf][(w*32   )*32]);      \
    async16(Wb + (size_t)(srow+16)*(K) + (kk) + scol, &lsB[buf][(w*32+16)*32]);

#define GEMM_FRAG_MFMA(cur)                                                          \
    bh8 af[4], bfx[4];                                                               \
    _Pragma("unroll")                                                                \
    for(int t=0;t<4;t++){                                                            \
      af[t]  = *(const bh8*)&lsA[cur][(wm*64+t*16+l15)*32 + rsw*8];                  \
      bfx[t] = *(const bh8*)&lsB[cur][(wn*64+t*16+l15)*32 + rsw*8];                  \
    }                                                                                \
    _Pragma("unroll")                                                                \
    for(int mt=0;mt<4;mt++)                                                          \
      _Pragma("unroll")                                                              \
      for(int nt=0;nt<4;nt++)                                                        \
        acc[mt][nt] = __builtin_amdgcn_mfma_f32_16x16x32_bf16(af[mt], bfx[nt], acc[mt][nt], 0,0,0);

// Counted-vmcnt raw-barrier loop (4 loads/stage -> vmcnt(4) steady state).
#define GEMM_KLOOP_CNT(Ab, Wb, K) {                                                  \
  const int srow = w*32 + (lane>>2);                                                 \
  const int scol = (((lane&3) ^ ((srow>>1)&3)) * 8);                                 \
  const int rsw  = ((l15>>1)&3) ^ quad;                                              \
  GEMM_STAGE(Ab, Wb, K, 0, 0)                                                        \
  const int NS = (K)>>5;                                                             \
  for(int j=0;j<NS;j++){                                                             \
    const int cur = j&1;                                                             \
    if(j+1<NS){                                                                      \
      GEMM_STAGE(Ab, Wb, K, (j+1)*32, cur^1)                                         \
      asm volatile("s_waitcnt vmcnt(4)" ::: "memory");                               \
    } else {                                                                         \
      asm volatile("s_waitcnt vmcnt(0)" ::: "memory");                               \
    }                                                                                \
    __builtin_amdgcn_s_barrier();                                                    \
    GEMM_FRAG_MFMA(cur)                                                              \
    __builtin_amdgcn_s_barrier();                                                    \
  } }

// Single-__syncthreads dbuf loop (best for EPI2 up-proj, R7/R9-proven).
#define GEMM_KLOOP_SYNC(Ab, Wb, K) {                                                 \
  const int srow = w*32 + (lane>>2);                                                 \
  const int scol = (((lane&3) ^ ((srow>>1)&3)) * 8);                                 \
  const int rsw  = ((l15>>1)&3) ^ quad;                                              \
  GEMM_STAGE(Ab, Wb, K, 0, 0)                                                        \
  __syncthreads();                                                                   \
  for(int k0=0;k0<K;k0+=32){                                                         \
    const int cur = (k0>>5)&1;                                                       \
    if(k0+32 < K){ GEMM_STAGE(Ab, Wb, K, k0+32, cur^1) }                             \
    GEMM_FRAG_MFMA(cur)                                                              \
    __syncthreads();                                                                 \
  } }

// ---- BN=64 K-loop: 128x64 tile, 4 waves stacked in M (each 32 rows x 64 cols). ----
// 3 loads/stage (A:2, B:1) -> vmcnt(3) steady state. LDS 24KB.
#define GEMM_STAGE64(Ab, Wb, K, kk, buf)                                             \
    async16(Ab + (size_t)srow*(K)      + (kk) + scol,  &lsA[buf][(w*32   )*32]);     \
    async16(Ab + (size_t)(srow+16)*(K) + (kk) + scol,  &lsA[buf][(w*32+16)*32]);     \
    async16(Wb + (size_t)browB*(K)     + (kk) + scolB, &lsB[buf][(w*16)*32]);

#define GEMM_KLOOP_CNT64(Ab, Wb, K) {                                                \
  const int srow  = w*32 + (lane>>2);                                                \
  const int scol  = (((lane&3) ^ ((srow>>1)&3)) * 8);                                \
  const int browB = w*16 + (lane>>2);                                                \
  const int scolB = (((lane&3) ^ ((browB>>1)&3)) * 8);                               \
  const int rsw   = ((l15>>1)&3) ^ quad;                                             \
  GEMM_STAGE64(Ab, Wb, K, 0, 0)                                                      \
  const int NS = (K)>>5;                                                             \
  for(int j=0;j<NS;j++){                                                             \
    const int cur = j&1;                                                             \
    if(j+1<NS){                                                                      \
      GEMM_STAGE64(Ab, Wb, K, (j+1)*32, cur^1)                                       \
      asm volatile("s_waitcnt vmcnt(3)" ::: "memory");                               \
    } else {                                                                         \
      asm volatile("s_waitcnt vmcnt(0)" ::: "memory");                               \
    }                                                                                \
    __builtin_amdgcn_s_barrier();                                                    \
    bh8 af[2], bfx[4];                                                               \
    _Pragma("unroll")                                                                \
    for(int t=0;t<2;t++)                                                             \
      af[t]  = *(const bh8*)&lsA[cur][(w*32+t*16+l15)*32 + rsw*8];                   \
    _Pragma("unroll")                                                                \
    for(int t=0;t<4;t++)                                                             \
      bfx[t] = *(const bh8*)&lsB[cur][(t*16+l15)*32 + rsw*8];                        \
    _Pragma("unroll")                                                                \
    for(int mt=0;mt<2;mt++)                                                          \
      _Pragma("unroll")                                                              \
      for(int nt=0;nt<4;nt++)                                                        \
        acc[mt][nt] = __builtin_amdgcn_mfma_f32_16x16x32_bf16(af[mt], bfx[nt], acc[mt][nt], 0,0,0); \
    __builtin_amdgcn_s_barrier();                                                    \
  } }

// ---------------- multi-output projection GEMM (BN=128): C_sub = A * W_sub^T + bias -------
// Input-set index i = bm>>7 selects W/bias/ksum offsets (CA kv: grid y=256; SA: y=128).
struct SubD { const float* bias; u16* out; float* ksum; int mode; };
struct Subs3 { SubD s[3]; };
__global__ __launch_bounds__(256) void gemm_qkv(const u16* __restrict__ A,
    const u16* __restrict__ W, Subs3 subs, int K, int wstride, int bstride, int ksstride){
  __shared__ __align__(16) u16 lsA[2][128*32];
  __shared__ __align__(16) u16 lsB[2][128*32];
  const int tid = threadIdx.x, lane = tid&63, w = tid>>6;
  const int quad = lane>>4, l15 = lane&15;
  const int2 swz = xcd_swz();
  const int bn = swz.x, bm = swz.y;
  const int iset = bm>>7;
  const int wm = w&1, wn = w>>1;
  fx4 acc[4][4];
  #pragma unroll
  for(int i=0;i<4;i++)
    #pragma unroll
    for(int j=0;j<4;j++) acc[i][j] = (fx4){0.f,0.f,0.f,0.f};
  const u16* Ab = A + (size_t)bm*128*K;
  const u16* Wb = W + (size_t)iset*wstride + (size_t)bn*128*K;
  GEMM_KLOOP_CNT(Ab, Wb, K)
  const SubD sub = subs.s[bn>>2];
  const int colw = (bn&3)*128 + wn*64;
  const float* bias = sub.bias + iset*bstride;
  float bcol[4];
  #pragma unroll
  for(int nt=0;nt<4;nt++) bcol[nt] = bias[colw + nt*16 + l15];

  if(sub.mode==1){
    float ksacc[4] = {0.f,0.f,0.f,0.f};
    #pragma unroll
    for(int mt=0;mt<4;mt++)
      #pragma unroll
      for(int r=0;r<4;r++){
        float v0=acc[mt][0][r]+bcol[0], v1=acc[mt][1][r]+bcol[1];
        float v2=acc[mt][2][r]+bcol[2], v3=acc[mt][3][r]+bcol[3];
        float mx = fmaxf(fmaxf(v0,v1),fmaxf(v2,v3));
        mx = fmaxf(mx,__shfl_xor(mx,1,64)); mx = fmaxf(mx,__shfl_xor(mx,2,64));
        mx = fmaxf(mx,__shfl_xor(mx,4,64)); mx = fmaxf(mx,__shfl_xor(mx,8,64));
        float e0=__expf(v0-mx), e1=__expf(v1-mx), e2=__expf(v2-mx), e3=__expf(v3-mx);
        float s = e0+e1+e2+e3;
        s += __shfl_xor(s,1,64); s += __shfl_xor(s,2,64);
        s += __shfl_xor(s,4,64); s += __shfl_xor(s,8,64);
        float inv = __fdividef(1.f, s);
        e0*=inv; e1*=inv; e2*=inv; e3*=inv;
        ksacc[0]+=e0; ksacc[1]+=e1; ksacc[2]+=e2; ksacc[3]+=e3;
        int row = bm*128 + wm*64 + mt*16 + quad*4 + r;
        size_t rb = (size_t)row*512;
        sub.out[rb+colw+ 0+l15]=f2bf(e0); sub.out[rb+colw+16+l15]=f2bf(e1);
        sub.out[rb+colw+32+l15]=f2bf(e2); sub.out[rb+colw+48+l15]=f2bf(e3);
      }
    if(sub.ksum){
      int b = (bm&127)>>5;
      float* ks = sub.ksum + iset*ksstride + b*512;
      #pragma unroll
      for(int nt=0;nt<4;nt++){
        float s = ksacc[nt];
        s += __shfl_xor(s,16,64); s += __shfl_xor(s,32,64);
        if(quad==0) atomicAdd(&ks[colw + nt*16 + l15], s);
      }
    }
  } else {
    #pragma unroll
    for(int mt=0;mt<4;mt++)
      #pragma unroll
      for(int r=0;r<4;r++){
        int row = bm*128 + wm*64 + mt*16 + quad*4 + r;
        size_t rb = (size_t)row*512;
        #pragma unroll
        for(int nt=0;nt<4;nt++)
          sub.out[rb + colw + nt*16 + l15] = f2bf(acc[mt][nt][r] + bcol[nt]);
      }
  }
}

// ---------------- CA q-proj (BN=64): softmax epilogue, grid (8,128) ----------------
__global__ __launch_bounds__(256) void gemm_q64(const u16* __restrict__ A,
    const u16* __restrict__ W, const float* __restrict__ bias, u16* __restrict__ out){
  __shared__ __align__(16) u16 lsA[2][128*32];
  __shared__ __align__(16) u16 lsB[2][64*32];
  const int tid = threadIdx.x, lane = tid&63, w = tid>>6;
  const int quad = lane>>4, l15 = lane&15;
  const int2 swz = xcd_swz();
  const int bn = swz.x, bm = swz.y;
  fx4 acc[2][4];
  #pragma unroll
  for(int i=0;i<2;i++)
    #pragma unroll
    for(int j=0;j<4;j++) acc[i][j] = (fx4){0.f,0.f,0.f,0.f};
  const u16* Ab = A + (size_t)bm*128*512;
  const u16* Wb = W + (size_t)bn*64*512;
  GEMM_KLOOP_CNT64(Ab, Wb, 512)
  const int colb = bn*64;
  float bcol[4];
  #pragma unroll
  for(int nt=0;nt<4;nt++) bcol[nt] = bias[colb + nt*16 + l15];
  #pragma unroll
  for(int mt=0;mt<2;mt++)
    #pragma unroll
    for(int r=0;r<4;r++){
      float v0=acc[mt][0][r]+bcol[0], v1=acc[mt][1][r]+bcol[1];
      float v2=acc[mt][2][r]+bcol[2], v3=acc[mt][3][r]+bcol[3];
      float mx = fmaxf(fmaxf(v0,v1),fmaxf(v2,v3));
      mx = fmaxf(mx,__shfl_xor(mx,1,64)); mx = fmaxf(mx,__shfl_xor(mx,2,64));
      mx = fmaxf(mx,__shfl_xor(mx,4,64)); mx = fmaxf(mx,__shfl_xor(mx,8,64));
      float e0=__expf(v0-mx), e1=__expf(v1-mx), e2=__expf(v2-mx), e3=__expf(v3-mx);
      float s = e0+e1+e2+e3;
      s += __shfl_xor(s,1,64); s += __shfl_xor(s,2,64);
      s += __shfl_xor(s,4,64); s += __shfl_xor(s,8,64);
      float inv = __fdividef(1.f, s);
      e0*=inv; e1*=inv; e2*=inv; e3*=inv;
      int row = bm*128 + w*32 + mt*16 + quad*4 + r;
      size_t rb = (size_t)row*512;
      out[rb+colb+ 0+l15]=f2bf(e0); out[rb+colb+16+l15]=f2bf(e1);
      out[rb+colb+32+l15]=f2bf(e2); out[rb+colb+48+l15]=f2bf(e3);
    }
}

// -------- out/down-proj (BN=64): C = A*W^T + bias + res -> fp32, grid (8,128) --------
__global__ __launch_bounds__(256) void gemm_dn64(const u16* __restrict__ A,
    const u16* __restrict__ W, const float* __restrict__ bias,
    const float* __restrict__ res, float* __restrict__ out, int N, int K){
  __shared__ __align__(16) u16 lsA[2][128*32];
  __shared__ __align__(16) u16 lsB[2][64*32];
  const int tid = threadIdx.x, lane = tid&63, w = tid>>6;
  const int quad = lane>>4, l15 = lane&15;
  const int2 swz = xcd_swz();
  const int bn = swz.x, bm = swz.y;
  fx4 acc[2][4];
  #pragma unroll
  for(int i=0;i<2;i++)
    #pragma unroll
    for(int j=0;j<4;j++) acc[i][j] = (fx4){0.f,0.f,0.f,0.f};
  const u16* Ab = A + (size_t)bm*128*K;
  const u16* Wb = W + (size_t)bn*64*K;
  GEMM_KLOOP_CNT64(Ab, Wb, K)
  const int colb = bn*64;
  float bcol[4];
  #pragma unroll
  for(int nt=0;nt<4;nt++) bcol[nt] = bias[colb + nt*16 + l15];
  #pragma unroll
  for(int mt=0;mt<2;mt++)
    #pragma unroll
    for(int r=0;r<4;r++){
      int row = bm*128 + w*32 + mt*16 + quad*4 + r;
      size_t rb = (size_t)row*N;
      #pragma unroll
      for(int nt=0;nt<4;nt++){
        int col = colb + nt*16 + l15;
        out[rb+col] = res[rb+col] + acc[mt][nt][r] + bcol[nt];
      }
    }
}

// ---------------- FFN up-proj: C = A*W^T + bias -> gelu -> bf16 (SYNC loop) ----------------
__global__ __launch_bounds__(256) void gemm_up(const u16* __restrict__ A,
    const u16* __restrict__ W, const float* __restrict__ bias,
    u16* __restrict__ out, int N, int K){
  __shared__ __align__(16) u16 lsA[2][128*32];
  __shared__ __align__(16) u16 lsB[2][128*32];
  const int tid = threadIdx.x, lane = tid&63, w = tid>>6;
  const int quad = lane>>4, l15 = lane&15;
  const int2 swz = xcd_swz();
  const int bn = swz.x, bm = swz.y;
  const int wm = w&1, wn = w>>1;
  fx4 acc[4][4];
  #pragma unroll
  for(int i=0;i<4;i++)
    #pragma unroll
    for(int j=0;j<4;j++) acc[i][j] = (fx4){0.f,0.f,0.f,0.f};
  const u16* Ab = A + (size_t)bm*128*K;
  const u16* Wb = W + (size_t)bn*128*K;
  GEMM_KLOOP_SYNC(Ab, Wb, K)
  const int colbase = bn*128 + wn*64;
  float bcol[4];
  #pragma unroll
  for(int nt=0;nt<4;nt++) bcol[nt] = bias[colbase + nt*16 + l15];
  #pragma unroll
  for(int mt=0;mt<4;mt++)
    #pragma unroll
    for(int r=0;r<4;r++){
      int row = bm*128 + wm*64 + mt*16 + quad*4 + r;
      size_t rb = (size_t)row*N;
      #pragma unroll
      for(int nt=0;nt<4;nt++)
        out[rb + colbase + nt*16 + l15] = f2bf(gelu_fast(acc[mt][nt][r] + bcol[nt]));
    }
}

// ---------------- ctx[i,b,h][d1][d2] = sum_t k[t][d1] v[t][d2] (MFMA over t) ----------------
__global__ __launch_bounds__(256) void ctx_kernel(const u16* __restrict__ kb,
    const u16* __restrict__ vb, float* __restrict__ ctx, size_t kstride){
  __shared__ __align__(16) u16 lk[64*72];  // transposed [d][t], stride 72
  __shared__ __align__(16) u16 lv[64*72];
  const int tid=threadIdx.x, lane=tid&63, w=tid>>6, quad=lane>>4, l15=lane&15;
  const int bh2 = blockIdx.x, i = bh2>>5, h = bh2&7, b = (bh2>>3)&3;
  const u16* kbase = kb + (size_t)i*kstride;
  const u16* vbase = vb + (size_t)i*kstride;
  const size_t rowbase = (size_t)b*4096 + (size_t)blockIdx.y*512;
  const int mt0=(w&1)*32, nt0=(w>>1)*32;
  fx4 acc[2][2];
  #pragma unroll
  for(int x=0;x<2;x++)
    #pragma unroll
    for(int j=0;j<2;j++) acc[x][j] = (fx4){0.f,0.f,0.f,0.f};
  const int tl = tid>>2, part = tid&3;
  for(int it=0; it<8; it++){
    __syncthreads();
    {
      size_t gro = (rowbase + it*64 + tl)*512 + h*64 + part*16;
      bh8 k0 = *(const bh8*)(kbase + gro); bh8 k1 = *(const bh8*)(kbase + gro + 8);
      bh8 v0 = *(const bh8*)(vbase + gro); bh8 v1 = *(const bh8*)(vbase + gro + 8);
      #pragma unroll
      for(int j=0;j<8;j++){
        lk[(part*16+j  )*72 + tl] = (u16)k0[j];
        lk[(part*16+8+j)*72 + tl] = (u16)k1[j];
        lv[(part*16+j  )*72 + tl] = (u16)v0[j];
        lv[(part*16+8+j)*72 + tl] = (u16)v1[j];
      }
    }
    __syncthreads();
    #pragma unroll
    for(int ks=0;ks<2;ks++){
      bh8 a0 = *(const bh8*)&lk[(mt0    +l15)*72 + ks*32 + quad*8];
      bh8 a1 = *(const bh8*)&lk[(mt0+16 +l15)*72 + ks*32 + quad*8];
      bh8 b0 = *(const bh8*)&lv[(nt0    +l15)*72 + ks*32 + quad*8];
      bh8 b1 = *(const bh8*)&lv[(nt0+16 +l15)*72 + ks*32 + quad*8];
      acc[0][0] = __builtin_amdgcn_mfma_f32_16x16x32_bf16(a0,b0,acc[0][0],0,0,0);
      acc[0][1] = __builtin_amdgcn_mfma_f32_16x16x32_bf16(a0,b1,acc[0][1],0,0,0);
      acc[1][0] = __builtin_amdgcn_mfma_f32_16x16x32_bf16(a1,b0,acc[1][0],0,0,0);
      acc[1][1] = __builtin_amdgcn_mfma_f32_16x16x32_bf16(a1,b1,acc[1][1],0,0,0);
    }
  }
  float* cb = ctx + (size_t)bh2*4096;
  #pragma unroll
  for(int mi=0;mi<2;mi++)
    #pragma unroll
    for(int ni=0;ni<2;ni++)
      #pragma unroll
      for(int r=0;r<4;r++){
        int d1 = mt0 + mi*16 + quad*4 + r;
        int d2 = nt0 + ni*16 + l15;
        atomicAdd(&cb[d1*64 + d2], acc[mi][ni][r]);
      }
}

// ------- out = q + sum_i (q @ ctx_i) * Dinv_i, Dinv fused (quad-shuffle over q frags) -------
template<int NIN>
__global__ __launch_bounds__(256) void apply_kernel(const u16* __restrict__ q,
    const float* __restrict__ ctx, const float* __restrict__ ksum, float eps,
    u16* __restrict__ out){
  __shared__ __align__(16) u16 lctx[(NIN+1)*64*72];
  const int tid=threadIdx.x, lane=tid&63, w=tid>>6, quad=lane>>4, l15=lane&15;
  const int bh = blockIdx.x, b=bh>>3, h=bh&7;
  {
    int base = tid*16;
    int d1 = base>>6, d2b = base&63;
    #pragma unroll
    for(int s=0;s<=NIN;s++){
      u16* dst = &lctx[s*64*72];
      if(s<NIN){
        const float* sp = ctx + ((size_t)s*32 + bh)*4096 + base;
        #pragma unroll
        for(int j=0;j<16;j++) dst[(d2b+j)*72 + d1] = f2bf(sp[j]);
      } else {
        #pragma unroll
        for(int j=0;j<16;j++) dst[(d2b+j)*72 + d1] = ((d2b+j)==d1) ? (u16)0x3f80 : (u16)0;
      }
    }
  }
  float kslo[NIN][8], kshi[NIN][8];
  #pragma unroll
  for(int s=0;s<NIN;s++){
    const float* ks = ksum + s*2048 + b*512 + h*64;
    #pragma unroll
    for(int j=0;j<8;j++){ kslo[s][j] = ks[quad*8+j]; kshi[s][j] = ks[32+quad*8+j]; }
  }
  __syncthreads();
  bh8 bfr[NIN+1][4][2];
  #pragma unroll
  for(int s=0;s<=NIN;s++)
    #pragma unroll
    for(int nt=0;nt<4;nt++)
      #pragma unroll
      for(int ks=0;ks<2;ks++)
        bfr[s][nt][ks] = *(const bh8*)&lctx[s*64*72 + (nt*16+l15)*72 + ks*32 + quad*8];
  const size_t tb0 = (size_t)b*4096 + (size_t)blockIdx.y*256 + w*64;
  for(int g=0;g<4;g++){
    size_t tb = tb0 + g*16;
    const u16* qr = q + (tb + l15)*512 + h*64;
    bh8 a0 = *(const bh8*)(qr + quad*8);
    bh8 a1 = *(const bh8*)(qr + 32 + quad*8);
    float dv[NIN][4];
    #pragma unroll
    for(int s=0;s<NIN;s++){
      float part = 0.f;
      #pragma unroll
      for(int j=0;j<8;j++)
        part += bf2f((u16)a0[j])*kslo[s][j] + bf2f((u16)a1[j])*kshi[s][j];
      part += __shfl_xor(part,16,64); part += __shfl_xor(part,32,64);
      #pragma unroll
      for(int r=0;r<4;r++)
        dv[s][r] = __fdividef(1.f, __shfl(part, quad*4+r, 64) + eps);
    }
    fx4 outv[4];
    #pragma unroll
    for(int nt=0;nt<4;nt++) outv[nt] = (fx4){0.f,0.f,0.f,0.f};
    #pragma unroll
    for(int s=0;s<=NIN;s++){
      fx4 c[4];
      #pragma unroll
      for(int nt=0;nt<4;nt++){
        c[nt] = (fx4){0.f,0.f,0.f,0.f};
        c[nt] = __builtin_amdgcn_mfma_f32_16x16x32_bf16(a0, bfr[s][nt][0], c[nt], 0,0,0);
        c[nt] = __builtin_amdgcn_mfma_f32_16x16x32_bf16(a1, bfr[s][nt][1], c[nt], 0,0,0);
      }
      #pragma unroll
      for(int nt=0;nt<4;nt++)
        #pragma unroll
        for(int r=0;r<4;r++) outv[nt][r] += c[nt][r]*((s==NIN)?1.f:dv[s][r]);
    }
    #pragma unroll
    for(int nt=0;nt<4;nt++)
      #pragma unroll
      for(int r=0;r<4;r++)
        out[(tb+quad*4+r)*512 + h*64 + nt*16 + l15] = f2bf(outv[nt][r]);
  }
}

// =========================================================================
extern "C" void kernel_launch(void* const* d_in, const int* in_sizes, int n_in,
                              void* d_out, int out_size, void* d_ws, size_t ws_size,
                              hipStream_t stream){
  const float* x_in =(const float*)d_in[0];
  const float* ys   =(const float*)d_in[1];
  const float* ln1g =(const float*)d_in[2],  *ln1b=(const float*)d_in[3];
  const float* ln2g =(const float*)d_in[4],  *ln2b=(const float*)d_in[5];
  const float* ln3g =(const float*)d_in[6],  *ln3b=(const float*)d_in[7];
  const float* ln4g =(const float*)d_in[8],  *ln4b=(const float*)d_in[9];
  const float* ln5g =(const float*)d_in[10], *ln5b=(const float*)d_in[11];
  const float* ca_wq=(const float*)d_in[12], *ca_bq=(const float*)d_in[13];
  const float* ca_wk=(const float*)d_in[14], *ca_bk=(const float*)d_in[15];
  const float* ca_wv=(const float*)d_in[16], *ca_bv=(const float*)d_in[17];
  const float* ca_wo=(const float*)d_in[18], *ca_bo=(const float*)d_in[19];
  const float* sa_wq=(const float*)d_in[20], *sa_bq=(const float*)d_in[21];
  const float* sa_wk=(const float*)d_in[22], *sa_bk=(const float*)d_in[23];
  const float* sa_wv=(const float*)d_in[24], *sa_bv=(const float*)d_in[25];
  const float* sa_wo=(const float*)d_in[26], *sa_bo=(const float*)d_in[27];
  const float* f1w1 =(const float*)d_in[28], *f1b1=(const float*)d_in[29];
  const float* f1w2 =(const float*)d_in[30], *f1b2=(const float*)d_in[31];
  const float* f2w1 =(const float*)d_in[32], *f2b1=(const float*)d_in[33];
  const float* f2w2 =(const float*)d_in[34], *f2b2=(const float*)d_in[35];

  char* p = (char*)d_ws;
  u16*   WBF = (u16*)p;    p += 13631488;   // bf16 weights
  float* XW  = (float*)p;  p += 33554432;   // residual stream fp32 [16384,512]
  u16*   XN2 = (u16*)p;    p += 33554432;   // LN out, up to 2x16384 rows
  u16*   QB  = (u16*)p;    p += 16777216;
  u16*   R1  = (u16*)p;    p += 67108864;   // FFN hidden [16384,2048] OR stacked KB2|VB2
  u16*   OUTB= (u16*)p;    p += 16777216;   // attention output (also stages CA x-LN)
  float* SM  = (float*)p;  p += 1597440;    // ctx + ksum (zeroed)
  u16*   XN  = XN2;
  u16*   KB2 = R1;
  u16*   VB2 = R1 + 16777216;
  u16*   HB  = R1;
  float* CTXC = SM;                          // [2][32][4096]
  float* CTXS = SM + 262144;                 // [32][4096]
  float* KSC  = SM + 393216;                 // [2][4][512]
  float* KSS  = SM + 397312;                 // [4][512]

  WDesc wd;
  const float* wsrc[14] = {ca_wq, ca_wk, ca_wv, ca_wk+262144, ca_wv+262144, ca_wo,
                           sa_wq, sa_wk, sa_wv, sa_wo, f1w1, f1w2, f2w1, f2w2};
  const int    woff[14] = {0, 262144, 524288, 786432, 1048576, 1310720,
                           1572864, 1835008, 2097152, 2359296,
                           2621440, 3670016, 4718592, 5767168};
  for(int i=0;i<14;i++){ wd.src[i]=wsrc[i]; wd.off[i]=woff[i]; }
  convw_kernel<<<26624,256,0,stream>>>(wd, WBF);
  hipMemsetAsync(SM, 0, 399360*sizeof(float), stream);

  SubD zsub = {nullptr,nullptr,nullptr,0};

  // ---- cross attention ----
  ln_kernel<<<4096,256,0,stream>>>(x_in, ln1g, ln1b, OUTB);   // x-LN staged in OUTB
  lny_kernel<<<8192,256,0,stream>>>(ys, ln2g, ln2b, XN2);     // both ys LNs
  gemm_q64<<<dim3(8,128),256,0,stream>>>(OUTB, WBF+0, ca_bq, QB);
  { Subs3 s = {{ {ca_bk, KB2, KSC, 1}, {ca_bv, VB2, nullptr, 0}, zsub }};
    gemm_qkv<<<dim3(8,256),256,0,stream>>>(XN2, WBF+262144, s, 512,
                                           524288, 512, 2048); }  // i = bm>>7
  ctx_kernel<<<dim3(64,8),256,0,stream>>>(KB2, VB2, CTXC, (size_t)16384*512);
  apply_kernel<2><<<dim3(32,16),256,0,stream>>>(QB, CTXC, KSC, 1e-8f, OUTB);
  gemm_dn64<<<dim3(8,128),256,0,stream>>>(OUTB, WBF+1310720, ca_bo, x_in, XW, 512, 512);

  // ---- FFN 1 ----
  ln_kernel<<<4096,256,0,stream>>>(XW, ln3g, ln3b, XN);
  gemm_up<<<dim3(16,128),256,0,stream>>>(XN, WBF+2621440, f1b1, HB, 2048, 512);
  gemm_dn64<<<dim3(8,128),256,0,stream>>>(HB, WBF+3670016, f1b2, XW, XW, 512, 2048);

  // ---- linear self attention ----
  ln_kernel<<<4096,256,0,stream>>>(XW, ln4g, ln4b, XN);
  { Subs3 s = {{ {sa_bq, QB, nullptr, 1}, {sa_bk, KB2, KSS, 1}, {sa_bv, VB2, nullptr, 0} }};
    gemm_qkv<<<dim3(12,128),256,0,stream>>>(XN, WBF+1572864, s, 512, 0,0,0); }
  ctx_kernel<<<dim3(32,8),256,0,stream>>>(KB2, VB2, CTXS, 0);
  apply_kernel<1><<<dim3(32,16),256,0,stream>>>(QB, CTXS, KSS, 0.f, OUTB);
  gemm_dn64<<<dim3(8,128),256,0,stream>>>(OUTB, WBF+2359296, sa_bo, XW, XW, 512, 512);

  // ---- FFN 2 ----
  ln_kernel<<<4096,256,0,stream>>>(XW, ln5g, ln5b, XN);
  gemm_up<<<dim3(16,128),256,0,stream>>>(XN, WBF+4718592, f2b1, HB, 2048, 512);
  gemm_dn64<<<dim3(8,128),256,0,stream>>>(HB, WBF+5767168, f2b2, XW, (float*)d_out, 512, 2048);
}

// Round 6
// 692.549 us; speedup vs baseline: 1.0325x; 1.0248x over previous
//
// CrossAttentionBlock_56813827392085 — fused transformer block, bf16 MFMA internals. R12:
//  = R11 dispatch structure + A-OPERANDS DIRECT FROM GLOBAL (fragment layout, no LDS):
//  R11's decisive null (occupancy 2x -> duration unchanged, MfmaUtil pinned 21%) + traffic
//  arithmetic (dn64: 46us of 64us is LDS traffic at the 52TB/s ds_read ceiling) shows the
//  GEMMs are LDS-bandwidth-bound. Fix: producers (ln/lny/up-epi/apply-epi) write A-buffers
//  (XN/XN2/HB/OUTB) in MFMA-fragment layout: elem(row,k) @ (row>>4)*16K+(k>>3)*128+
//  (row&15)*8+(k&7), so a wave's 16x32 A-frag is contiguous 1KB at tile*16K+k0*16+lane*8 —
//  coalesced global->VGPR load, register-double-buffered. Only B (weights) stays in LDS.
//  LDS traffic/step: 0.5-0.55x. Counted vmcnt re-derived (B oldest): 128^2 vmcnt(10),
//  BN=64 vmcnt(5); A-loads are compiler-tracked (auto-waits), only gload_lds needs counts.
//  QB/KB/VB outputs stay row-major (ctx/apply consume them). Same arithmetic -> same absmax.
#include <hip/hip_runtime.h>
#include <hip/hip_bf16.h>
#include <math.h>
#include <stdint.h>

typedef unsigned short u16;
typedef __attribute__((ext_vector_type(8))) short bh8;
typedef __attribute__((ext_vector_type(4))) float fx4;

#define DEV static __device__ __forceinline__

DEV float bf2f(u16 u){ union{unsigned u; float f;} v; v.u = ((unsigned)u)<<16; return v.f; }
DEV u16 f2bf(float f){ union{float f; unsigned u;} v; v.f = f;
  return (u16)((v.u + 0x7fffu + ((v.u>>16)&1u))>>16); }               // RNE

DEV void async16(const u16* g, u16* l){
  __builtin_amdgcn_global_load_lds((__attribute__((address_space(1))) void*)(uintptr_t)g,
                                   (__attribute__((address_space(3))) void*)l, 16, 0, 0);
}

// MFMA-A fragment address for a [rows][Kbuf] bf16 buffer.
DEV size_t faddr(int row, int col, int Kbuf){
  return (size_t)(row>>4)*((size_t)Kbuf*16)
       + (size_t)((col>>3)*128 + (row&15)*8 + (col&7));
}

// gelu tanh-approx via sigmoid identity: x * 1/(1+exp(x*(-1.59577 - 0.0713548*x^2)))
DEV float gelu_fast(float x){
  float x2 = x*x;
  float t  = __builtin_fmaf(x2, -0.071354816f, -1.5957691216f);
  float e  = __expf(x*t);
  return __fdividef(x, 1.f + e);
}

// XCD-aware bijective block swizzle (requires nwg%8==0 — all GEMM grids here satisfy).
DEV int2 xcd_swz(){
  const int gx  = gridDim.x;
  const int ord = blockIdx.y*gx + blockIdx.x;
  const int nwg = gx*gridDim.y;
  const int wg  = (ord&7)*(nwg>>3) + (ord>>3);
  int2 r; r.x = wg % gx; r.y = wg / gx; return r;
}

// ---------------- weight fp32 -> bf16 pack ----------------
struct WDesc { const float* src[14]; int off[14]; };
__global__ __launch_bounds__(256) void convw_kernel(WDesc d, u16* __restrict__ dst){
  int i = blockIdx.x*256 + threadIdx.x;
  int s = 0;
  #pragma unroll
  for(int j=1;j<14;j++) if(i >= d.off[j]) s = j;
  dst[i] = f2bf(d.src[s][i - d.off[s]]);
}

// ---------------- LayerNorm (C=512), fp32 in -> bf16 FRAGMENT-layout out ----------------
DEV float wsum64(float s){
  s += __shfl_xor(s,1,64);  s += __shfl_xor(s,2,64);  s += __shfl_xor(s,4,64);
  s += __shfl_xor(s,8,64);  s += __shfl_xor(s,16,64); s += __shfl_xor(s,32,64);
  return s;
}
// orow = out + (row>>4)*8192 + (row&15)*8 ; lane l covers k=l*8..l*8+7 at +l*128.
DEV void ln_row(const float* xrow, const float* g, const float* bta, u16* orow, int lane){
  const float4* xr = (const float4*)xrow + lane*2;
  float4 a = xr[0], c = xr[1];
  float s = a.x+a.y+a.z+a.w + c.x+c.y+c.z+c.w;
  float mean = wsum64(s) * (1.f/512.f);
  float d0=a.x-mean,d1=a.y-mean,d2=a.z-mean,d3=a.w-mean;
  float d4=c.x-mean,d5=c.y-mean,d6=c.z-mean,d7=c.w-mean;
  float sv = d0*d0+d1*d1+d2*d2+d3*d3+d4*d4+d5*d5+d6*d6+d7*d7;
  float rstd = rsqrtf(wsum64(sv)*(1.f/512.f) + 1e-5f);
  const float4* gr = (const float4*)g   + lane*2;
  const float4* br = (const float4*)bta + lane*2;
  float4 g0=gr[0], g1=gr[1], b0=br[0], b1=br[1];
  bh8 o;
  o[0]=(short)f2bf(d0*rstd*g0.x+b0.x); o[1]=(short)f2bf(d1*rstd*g0.y+b0.y);
  o[2]=(short)f2bf(d2*rstd*g0.z+b0.z); o[3]=(short)f2bf(d3*rstd*g0.w+b0.w);
  o[4]=(short)f2bf(d4*rstd*g1.x+b1.x); o[5]=(short)f2bf(d5*rstd*g1.y+b1.y);
  o[6]=(short)f2bf(d6*rstd*g1.z+b1.z); o[7]=(short)f2bf(d7*rstd*g1.w+b1.w);
  *(bh8*)(orow + (size_t)lane*128) = o;
}
__global__ __launch_bounds__(256) void ln_kernel(const float* __restrict__ x,
    const float* __restrict__ g, const float* __restrict__ bta, u16* __restrict__ out){
  int row  = blockIdx.x*4 + (threadIdx.x>>6);
  u16* orow = out + (size_t)(row>>4)*8192 + (size_t)(row&15)*8;
  ln_row(x + (size_t)row*512, g, bta, orow, threadIdx.x&63);
}
__global__ __launch_bounds__(256) void lny_kernel(const float* __restrict__ ys,
    const float* __restrict__ g2, const float* __restrict__ b2, u16* __restrict__ out){
  int row  = blockIdx.x*4 + (threadIdx.x>>6);
  int i = row>>14;
  u16* orow = out + (size_t)(row>>4)*8192 + (size_t)(row&15)*8;
  ln_row(ys + (size_t)row*512, g2 + i*512, b2 + i*512, orow, threadIdx.x&63);
}

// ==== GEMM K-loop pieces: B staged in LDS (swizzled, conflict-free), A direct-global ====
// C/D layout: out_row = quad*4+r (within 16), out_col = l15.
#define BSTAGE128(Wb, K, kk, buf)                                                    \
    async16(Wb + (size_t)srow*(K)      + (kk) + scol, &lsB[buf][(w*32   )*32]);      \
    async16(Wb + (size_t)(srow+16)*(K) + (kk) + scol, &lsB[buf][(w*32+16)*32]);

#define APREF4(AF, K, kk)                                                            \
    _Pragma("unroll")                                                                \
    for(int t=0;t<4;t++)                                                             \
      AF[t] = *(const bh8*)(Alane + (size_t)t*16*(K) + (size_t)(kk)*16);

#define MFMA128(AF, CUR)                                                             \
    { bh8 bfx[4];                                                                    \
      _Pragma("unroll")                                                              \
      for(int t=0;t<4;t++)                                                           \
        bfx[t] = *(const bh8*)&lsB[CUR][(wn*64+t*16+l15)*32 + rsw*8];                \
      _Pragma("unroll")                                                              \
      for(int mt=0;mt<4;mt++)                                                        \
        _Pragma("unroll")                                                            \
        for(int nt=0;nt<4;nt++)                                                      \
          acc[mt][nt] = __builtin_amdgcn_mfma_f32_16x16x32_bf16(AF[mt], bfx[nt], acc[mt][nt], 0,0,0); }

// counted step: ages B(j)=2(old), A(j)=4, B(j+1)=2, A(j+1)=4 -> vmcnt(10) completes B(j).
#define CSTEP128(AFU, AFP, CUR, jj, Wb, K)                                           \
    if((jj)+1<NS){                                                                   \
      BSTAGE128(Wb, K, ((jj)+1)*32, (CUR)^1)                                         \
      asm volatile("" ::: "memory");                                                 \
      APREF4(AFP, K, ((jj)+1)*32)                                                    \
      asm volatile("s_waitcnt vmcnt(10)" ::: "memory");                              \
    } else {                                                                         \
      asm volatile("s_waitcnt vmcnt(0)" ::: "memory");                               \
    }                                                                                \
    __builtin_amdgcn_s_barrier();                                                    \
    MFMA128(AFU, CUR)                                                                \
    __builtin_amdgcn_s_barrier();

#define KLOOP_CNT128(Ab, Wb, K, WTILE)                                               \
  const int srow = w*32 + (lane>>2);                                                 \
  const int scol = (((lane&3) ^ ((srow>>1)&3)) * 8);                                 \
  const int rsw  = ((l15>>1)&3) ^ quad;                                              \
  const u16* Alane = (Ab) + (size_t)(WTILE)*16*(K) + lane*8;                         \
  bh8 afA[4], afB[4];                                                                \
  BSTAGE128(Wb, K, 0, 0)                                                             \
  asm volatile("" ::: "memory");                                                     \
  APREF4(afA, K, 0)                                                                  \
  const int NS = (K)>>5;                                                             \
  for(int j=0;j<NS;j+=2){                                                            \
    CSTEP128(afA, afB, 0, j,   Wb, K)                                                \
    CSTEP128(afB, afA, 1, j+1, Wb, K)                                                \
  }

// SYNC variant (proven best for the gelu up-proj): __syncthreads drains everything.
#define SSTEP128(AFU, AFP, CUR, jj, Wb, K)                                           \
    if((jj)+1<NS){                                                                   \
      BSTAGE128(Wb, K, ((jj)+1)*32, (CUR)^1)                                         \
      APREF4(AFP, K, ((jj)+1)*32)                                                    \
    }                                                                                \
    MFMA128(AFU, CUR)                                                                \
    __syncthreads();

#define KLOOP_SYNC128(Ab, Wb, K, WTILE)                                              \
  const int srow = w*32 + (lane>>2);                                                 \
  const int scol = (((lane&3) ^ ((srow>>1)&3)) * 8);                                 \
  const int rsw  = ((l15>>1)&3) ^ quad;                                              \
  const u16* Alane = (Ab) + (size_t)(WTILE)*16*(K) + lane*8;                         \
  bh8 afA[4], afB[4];                                                                \
  BSTAGE128(Wb, K, 0, 0)                                                             \
  APREF4(afA, K, 0)                                                                  \
  __syncthreads();                                                                   \
  const int NS = (K)>>5;                                                             \
  for(int j=0;j<NS;j+=2){                                                            \
    SSTEP128(afA, afB, 0, j,   Wb, K)                                                \
    SSTEP128(afB, afA, 1, j+1, Wb, K)                                                \
  }

// BN=64: 4 waves stacked in M (each 32 rows x 64 cols). B stage=1, A loads=2 -> vmcnt(5).
#define BSTAGE64(Wb, K, kk, buf)                                                     \
    async16(Wb + (size_t)browB*(K) + (kk) + scolB, &lsB[buf][(w*16)*32]);

#define APREF2(AF, K, kk)                                                            \
    _Pragma("unroll")                                                                \
    for(int t=0;t<2;t++)                                                             \
      AF[t] = *(const bh8*)(Alane + (size_t)t*16*(K) + (size_t)(kk)*16);

#define MFMA64(AF, CUR)                                                              \
    { bh8 bfx[4];                                                                    \
      _Pragma("unroll")                                                              \
      for(int t=0;t<4;t++)                                                           \
        bfx[t] = *(const bh8*)&lsB[CUR][(t*16+l15)*32 + rsw*8];                      \
      _Pragma("unroll")                                                              \
      for(int mt=0;mt<2;mt++)                                                        \
        _Pragma("unroll")                                                            \
        for(int nt=0;nt<4;nt++)                                                      \
          acc[mt][nt] = __builtin_amdgcn_mfma_f32_16x16x32_bf16(AF[mt], bfx[nt], acc[mt][nt], 0,0,0); }

#define CSTEP64(AFU, AFP, CUR, jj, Wb, K)                                            \
    if((jj)+1<NS){                                                                   \
      BSTAGE64(Wb, K, ((jj)+1)*32, (CUR)^1)                                          \
      asm volatile("" ::: "memory");                                                 \
      APREF2(AFP, K, ((jj)+1)*32)                                                    \
      asm volatile("s_waitcnt vmcnt(5)" ::: "memory");                               \
    } else {                                                                         \
      asm volatile("s_waitcnt vmcnt(0)" ::: "memory");                               \
    }                                                                                \
    __builtin_amdgcn_s_barrier();                                                    \
    MFMA64(AFU, CUR)                                                                 \
    __builtin_amdgcn_s_barrier();

#define KLOOP_CNT64(Ab, Wb, K)                                                       \
  const int browB = w*16 + (lane>>2);                                                \
  const int scolB = (((lane&3) ^ ((browB>>1)&3)) * 8);                               \
  const int rsw   = ((l15>>1)&3) ^ quad;                                             \
  const u16* Alane = (Ab) + (size_t)(w*2)*16*(K) + lane*8;                           \
  bh8 afA[2], afB[2];                                                                \
  BSTAGE64(Wb, K, 0, 0)                                                              \
  asm volatile("" ::: "memory");                                                     \
  APREF2(afA, K, 0)                                                                  \
  const int NS = (K)>>5;                                                             \
  for(int j=0;j<NS;j+=2){                                                            \
    CSTEP64(afA, afB, 0, j,   Wb, K)                                                 \
    CSTEP64(afB, afA, 1, j+1, Wb, K)                                                 \
  }

// ---------------- multi-output projection GEMM (BN=128, A frag-layout) ----------------
struct SubD { const float* bias; u16* out; float* ksum; int mode; };
struct Subs3 { SubD s[3]; };
__global__ __launch_bounds__(256) void gemm_qkv(const u16* __restrict__ A,
    const u16* __restrict__ W, Subs3 subs, int K, int wstride, int bstride, int ksstride){
  __shared__ __align__(16) u16 lsB[2][128*32];
  const int tid = threadIdx.x, lane = tid&63, w = tid>>6;
  const int quad = lane>>4, l15 = lane&15;
  const int2 swz = xcd_swz();
  const int bn = swz.x, bm = swz.y;
  const int iset = bm>>7;
  const int wm = w&1, wn = w>>1;
  fx4 acc[4][4];
  #pragma unroll
  for(int i=0;i<4;i++)
    #pragma unroll
    for(int j=0;j<4;j++) acc[i][j] = (fx4){0.f,0.f,0.f,0.f};
  const u16* Ab = A + (size_t)bm*128*K;      // == frag tile (bm*8) base
  const u16* Wb = W + (size_t)iset*wstride + (size_t)bn*128*K;
  KLOOP_CNT128(Ab, Wb, K, wm*4)
  const SubD sub = subs.s[bn>>2];
  const int colw = (bn&3)*128 + wn*64;
  const float* bias = sub.bias + iset*bstride;
  float bcol[4];
  #pragma unroll
  for(int nt=0;nt<4;nt++) bcol[nt] = bias[colw + nt*16 + l15];

  if(sub.mode==1){
    float ksacc[4] = {0.f,0.f,0.f,0.f};
    #pragma unroll
    for(int mt=0;mt<4;mt++)
      #pragma unroll
      for(int r=0;r<4;r++){
        float v0=acc[mt][0][r]+bcol[0], v1=acc[mt][1][r]+bcol[1];
        float v2=acc[mt][2][r]+bcol[2], v3=acc[mt][3][r]+bcol[3];
        float mx = fmaxf(fmaxf(v0,v1),fmaxf(v2,v3));
        mx = fmaxf(mx,__shfl_xor(mx,1,64)); mx = fmaxf(mx,__shfl_xor(mx,2,64));
        mx = fmaxf(mx,__shfl_xor(mx,4,64)); mx = fmaxf(mx,__shfl_xor(mx,8,64));
        float e0=__expf(v0-mx), e1=__expf(v1-mx), e2=__expf(v2-mx), e3=__expf(v3-mx);
        float s = e0+e1+e2+e3;
        s += __shfl_xor(s,1,64); s += __shfl_xor(s,2,64);
        s += __shfl_xor(s,4,64); s += __shfl_xor(s,8,64);
        float inv = __fdividef(1.f, s);
        e0*=inv; e1*=inv; e2*=inv; e3*=inv;
        ksacc[0]+=e0; ksacc[1]+=e1; ksacc[2]+=e2; ksacc[3]+=e3;
        int row = bm*128 + wm*64 + mt*16 + quad*4 + r;
        size_t rb = (size_t)row*512;
        sub.out[rb+colw+ 0+l15]=f2bf(e0); sub.out[rb+colw+16+l15]=f2bf(e1);
        sub.out[rb+colw+32+l15]=f2bf(e2); sub.out[rb+colw+48+l15]=f2bf(e3);
      }
    if(sub.ksum){
      int b = (bm&127)>>5;
      float* ks = sub.ksum + iset*ksstride + b*512;
      #pragma unroll
      for(int nt=0;nt<4;nt++){
        float s = ksacc[nt];
        s += __shfl_xor(s,16,64); s += __shfl_xor(s,32,64);
        if(quad==0) atomicAdd(&ks[colw + nt*16 + l15], s);
      }
    }
  } else {
    #pragma unroll
    for(int mt=0;mt<4;mt++)
      #pragma unroll
      for(int r=0;r<4;r++){
        int row = bm*128 + wm*64 + mt*16 + quad*4 + r;
        size_t rb = (size_t)row*512;
        #pragma unroll
        for(int nt=0;nt<4;nt++)
          sub.out[rb + colw + nt*16 + l15] = f2bf(acc[mt][nt][r] + bcol[nt]);
      }
  }
}

// ---------------- CA q-proj (BN=64): softmax epilogue, grid (8,128) ----------------
__global__ __launch_bounds__(256) void gemm_q64(const u16* __restrict__ A,
    const u16* __restrict__ W, const float* __restrict__ bias, u16* __restrict__ out){
  __shared__ __align__(16) u16 lsB[2][64*32];
  const int tid = threadIdx.x, lane = tid&63, w = tid>>6;
  const int quad = lane>>4, l15 = lane&15;
  const int2 swz = xcd_swz();
  const int bn = swz.x, bm = swz.y;
  fx4 acc[2][4];
  #pragma unroll
  for(int i=0;i<2;i++)
    #pragma unroll
    for(int j=0;j<4;j++) acc[i][j] = (fx4){0.f,0.f,0.f,0.f};
  const u16* Ab = A + (size_t)bm*128*512;
  const u16* Wb = W + (size_t)bn*64*512;
  KLOOP_CNT64(Ab, Wb, 512)
  const int colb = bn*64;
  float bcol[4];
  #pragma unroll
  for(int nt=0;nt<4;nt++) bcol[nt] = bias[colb + nt*16 + l15];
  #pragma unroll
  for(int mt=0;mt<2;mt++)
    #pragma unroll
    for(int r=0;r<4;r++){
      float v0=acc[mt][0][r]+bcol[0], v1=acc[mt][1][r]+bcol[1];
      float v2=acc[mt][2][r]+bcol[2], v3=acc[mt][3][r]+bcol[3];
      float mx = fmaxf(fmaxf(v0,v1),fmaxf(v2,v3));
      mx = fmaxf(mx,__shfl_xor(mx,1,64)); mx = fmaxf(mx,__shfl_xor(mx,2,64));
      mx = fmaxf(mx,__shfl_xor(mx,4,64)); mx = fmaxf(mx,__shfl_xor(mx,8,64));
      float e0=__expf(v0-mx), e1=__expf(v1-mx), e2=__expf(v2-mx), e3=__expf(v3-mx);
      float s = e0+e1+e2+e3;
      s += __shfl_xor(s,1,64); s += __shfl_xor(s,2,64);
      s += __shfl_xor(s,4,64); s += __shfl_xor(s,8,64);
      float inv = __fdividef(1.f, s);
      e0*=inv; e1*=inv; e2*=inv; e3*=inv;
      int row = bm*128 + w*32 + mt*16 + quad*4 + r;
      size_t rb = (size_t)row*512;
      out[rb+colb+ 0+l15]=f2bf(e0); out[rb+colb+16+l15]=f2bf(e1);
      out[rb+colb+32+l15]=f2bf(e2); out[rb+colb+48+l15]=f2bf(e3);
    }
}

// -------- out/down-proj (BN=64): C = A*W^T + bias + res -> fp32 row-major --------
__global__ __launch_bounds__(256) void gemm_dn64(const u16* __restrict__ A,
    const u16* __restrict__ W, const float* __restrict__ bias,
    const float* __restrict__ res, float* __restrict__ out, int N, int K){
  __shared__ __align__(16) u16 lsB[2][64*32];
  const int tid = threadIdx.x, lane = tid&63, w = tid>>6;
  const int quad = lane>>4, l15 = lane&15;
  const int2 swz = xcd_swz();
  const int bn = swz.x, bm = swz.y;
  fx4 acc[2][4];
  #pragma unroll
  for(int i=0;i<2;i++)
    #pragma unroll
    for(int j=0;j<4;j++) acc[i][j] = (fx4){0.f,0.f,0.f,0.f};
  const u16* Ab = A + (size_t)bm*128*K;
  const u16* Wb = W + (size_t)bn*64*K;
  KLOOP_CNT64(Ab, Wb, K)
  const int colb = bn*64;
  float bcol[4];
  #pragma unroll
  for(int nt=0;nt<4;nt++) bcol[nt] = bias[colb + nt*16 + l15];
  #pragma unroll
  for(int mt=0;mt<2;mt++)
    #pragma unroll
    for(int r=0;r<4;r++){
      int row = bm*128 + w*32 + mt*16 + quad*4 + r;
      size_t rb = (size_t)row*N;
      #pragma unroll
      for(int nt=0;nt<4;nt++){
        int col = colb + nt*16 + l15;
        out[rb+col] = res[rb+col] + acc[mt][nt][r] + bcol[nt];
      }
    }
}

// ------- FFN up-proj: C = A*W^T + bias -> gelu -> bf16 FRAGMENT layout (SYNC loop) -------
__global__ __launch_bounds__(256) void gemm_up(const u16* __restrict__ A,
    const u16* __restrict__ W, const float* __restrict__ bias,
    u16* __restrict__ out, int N, int K){
  __shared__ __align__(16) u16 lsB[2][128*32];
  const int tid = threadIdx.x, lane = tid&63, w = tid>>6;
  const int quad = lane>>4, l15 = lane&15;
  const int2 swz = xcd_swz();
  const int bn = swz.x, bm = swz.y;
  const int wm = w&1, wn = w>>1;
  fx4 acc[4][4];
  #pragma unroll
  for(int i=0;i<4;i++)
    #pragma unroll
    for(int j=0;j<4;j++) acc[i][j] = (fx4){0.f,0.f,0.f,0.f};
  const u16* Ab = A + (size_t)bm*128*K;
  const u16* Wb = W + (size_t)bn*128*K;
  KLOOP_SYNC128(Ab, Wb, K, wm*4)
  const int colbase = bn*128 + wn*64;
  float bcol[4];
  #pragma unroll
  for(int nt=0;nt<4;nt++) bcol[nt] = bias[colbase + nt*16 + l15];
  #pragma unroll
  for(int mt=0;mt<4;mt++)
    #pragma unroll
    for(int r=0;r<4;r++){
      int row = bm*128 + wm*64 + mt*16 + quad*4 + r;
      #pragma unroll
      for(int nt=0;nt<4;nt++){
        int col = colbase + nt*16 + l15;
        out[faddr(row, col, N)] = f2bf(gelu_fast(acc[mt][nt][r] + bcol[nt]));
      }
    }
}

// ---------------- ctx[i,b,h][d1][d2] = sum_t k[t][d1] v[t][d2] (MFMA over t) ----------------
__global__ __launch_bounds__(256) void ctx_kernel(const u16* __restrict__ kb,
    const u16* __restrict__ vb, float* __restrict__ ctx, size_t kstride){
  __shared__ __align__(16) u16 lk[64*72];  // transposed [d][t], stride 72
  __shared__ __align__(16) u16 lv[64*72];
  const int tid=threadIdx.x, lane=tid&63, w=tid>>6, quad=lane>>4, l15=lane&15;
  const int bh2 = blockIdx.x, i = bh2>>5, h = bh2&7, b = (bh2>>3)&3;
  const u16* kbase = kb + (size_t)i*kstride;
  const u16* vbase = vb + (size_t)i*kstride;
  const size_t rowbase = (size_t)b*4096 + (size_t)blockIdx.y*512;
  const int mt0=(w&1)*32, nt0=(w>>1)*32;
  fx4 acc[2][2];
  #pragma unroll
  for(int x=0;x<2;x++)
    #pragma unroll
    for(int j=0;j<2;j++) acc[x][j] = (fx4){0.f,0.f,0.f,0.f};
  const int tl = tid>>2, part = tid&3;
  for(int it=0; it<8; it++){
    __syncthreads();
    {
      size_t gro = (rowbase + it*64 + tl)*512 + h*64 + part*16;
      bh8 k0 = *(const bh8*)(kbase + gro); bh8 k1 = *(const bh8*)(kbase + gro + 8);
      bh8 v0 = *(const bh8*)(vbase + gro); bh8 v1 = *(const bh8*)(vbase + gro + 8);
      #pragma unroll
      for(int j=0;j<8;j++){
        lk[(part*16+j  )*72 + tl] = (u16)k0[j];
        lk[(part*16+8+j)*72 + tl] = (u16)k1[j];
        lv[(part*16+j  )*72 + tl] = (u16)v0[j];
        lv[(part*16+8+j)*72 + tl] = (u16)v1[j];
      }
    }
    __syncthreads();
    #pragma unroll
    for(int ks=0;ks<2;ks++){
      bh8 a0 = *(const bh8*)&lk[(mt0    +l15)*72 + ks*32 + quad*8];
      bh8 a1 = *(const bh8*)&lk[(mt0+16 +l15)*72 + ks*32 + quad*8];
      bh8 b0 = *(const bh8*)&lv[(nt0    +l15)*72 + ks*32 + quad*8];
      bh8 b1 = *(const bh8*)&lv[(nt0+16 +l15)*72 + ks*32 + quad*8];
      acc[0][0] = __builtin_amdgcn_mfma_f32_16x16x32_bf16(a0,b0,acc[0][0],0,0,0);
      acc[0][1] = __builtin_amdgcn_mfma_f32_16x16x32_bf16(a0,b1,acc[0][1],0,0,0);
      acc[1][0] = __builtin_amdgcn_mfma_f32_16x16x32_bf16(a1,b0,acc[1][0],0,0,0);
      acc[1][1] = __builtin_amdgcn_mfma_f32_16x16x32_bf16(a1,b1,acc[1][1],0,0,0);
    }
  }
  float* cb = ctx + (size_t)bh2*4096;
  #pragma unroll
  for(int mi=0;mi<2;mi++)
    #pragma unroll
    for(int ni=0;ni<2;ni++)
      #pragma unroll
      for(int r=0;r<4;r++){
        int d1 = mt0 + mi*16 + quad*4 + r;
        int d2 = nt0 + ni*16 + l15;
        atomicAdd(&cb[d1*64 + d2], acc[mi][ni][r]);
      }
}

// --- out = q + sum_i (q @ ctx_i)*Dinv_i; writes OUTB in FRAGMENT layout (K=512) ---
template<int NIN>
__global__ __launch_bounds__(256) void apply_kernel(const u16* __restrict__ q,
    const float* __restrict__ ctx, const float* __restrict__ ksum, float eps,
    u16* __restrict__ out){
  __shared__ __align__(16) u16 lctx[(NIN+1)*64*72];
  const int tid=threadIdx.x, lane=tid&63, w=tid>>6, quad=lane>>4, l15=lane&15;
  const int bh = blockIdx.x, b=bh>>3, h=bh&7;
  {
    int base = tid*16;
    int d1 = base>>6, d2b = base&63;
    #pragma unroll
    for(int s=0;s<=NIN;s++){
      u16* dst = &lctx[s*64*72];
      if(s<NIN){
        const float* sp = ctx + ((size_t)s*32 + bh)*4096 + base;
        #pragma unroll
        for(int j=0;j<16;j++) dst[(d2b+j)*72 + d1] = f2bf(sp[j]);
      } else {
        #pragma unroll
        for(int j=0;j<16;j++) dst[(d2b+j)*72 + d1] = ((d2b+j)==d1) ? (u16)0x3f80 : (u16)0;
      }
    }
  }
  float kslo[NIN][8], kshi[NIN][8];
  #pragma unroll
  for(int s=0;s<NIN;s++){
    const float* ks = ksum + s*2048 + b*512 + h*64;
    #pragma unroll
    for(int j=0;j<8;j++){ kslo[s][j] = ks[quad*8+j]; kshi[s][j] = ks[32+quad*8+j]; }
  }
  __syncthreads();
  bh8 bfr[NIN+1][4][2];
  #pragma unroll
  for(int s=0;s<=NIN;s++)
    #pragma unroll
    for(int nt=0;nt<4;nt++)
      #pragma unroll
      for(int ks=0;ks<2;ks++)
        bfr[s][nt][ks] = *(const bh8*)&lctx[s*64*72 + (nt*16+l15)*72 + ks*32 + quad*8];
  const size_t tb0 = (size_t)b*4096 + (size_t)blockIdx.y*256 + w*64;
  for(int g=0;g<4;g++){
    size_t tb = tb0 + g*16;
    const u16* qr = q + (tb + l15)*512 + h*64;
    bh8 a0 = *(const bh8*)(qr + quad*8);
    bh8 a1 = *(const bh8*)(qr + 32 + quad*8);
    float dv[NIN][4];
    #pragma unroll
    for(int s=0;s<NIN;s++){
      float part = 0.f;
      #pragma unroll
      for(int j=0;j<8;j++)
        part += bf2f((u16)a0[j])*kslo[s][j] + bf2f((u16)a1[j])*kshi[s][j];
      part += __shfl_xor(part,16,64); part += __shfl_xor(part,32,64);
      #pragma unroll
      for(int r=0;r<4;r++)
        dv[s][r] = __fdividef(1.f, __shfl(part, quad*4+r, 64) + eps);
    }
    fx4 outv[4];
    #pragma unroll
    for(int nt=0;nt<4;nt++) outv[nt] = (fx4){0.f,0.f,0.f,0.f};
    #pragma unroll
    for(int s=0;s<=NIN;s++){
      fx4 c[4];
      #pragma unroll
      for(int nt=0;nt<4;nt++){
        c[nt] = (fx4){0.f,0.f,0.f,0.f};
        c[nt] = __builtin_amdgcn_mfma_f32_16x16x32_bf16(a0, bfr[s][nt][0], c[nt], 0,0,0);
        c[nt] = __builtin_amdgcn_mfma_f32_16x16x32_bf16(a1, bfr[s][nt][1], c[nt], 0,0,0);
      }
      #pragma unroll
      for(int nt=0;nt<4;nt++)
        #pragma unroll
        for(int r=0;r<4;r++) outv[nt][r] += c[nt][r]*((s==NIN)?1.f:dv[s][r]);
    }
    #pragma unroll
    for(int nt=0;nt<4;nt++)
      #pragma unroll
      for(int r=0;r<4;r++)
        out[faddr((int)tb + quad*4 + r, h*64 + nt*16 + l15, 512)] = f2bf(outv[nt][r]);
  }
}

// =========================================================================
extern "C" void kernel_launch(void* const* d_in, const int* in_sizes, int n_in,
                              void* d_out, int out_size, void* d_ws, size_t ws_size,
                              hipStream_t stream){
  const float* x_in =(const float*)d_in[0];
  const float* ys   =(const float*)d_in[1];
  const float* ln1g =(const float*)d_in[2],  *ln1b=(const float*)d_in[3];
  const float* ln2g =(const float*)d_in[4],  *ln2b=(const float*)d_in[5];
  const float* ln3g =(const float*)d_in[6],  *ln3b=(const float*)d_in[7];
  const float* ln4g =(const float*)d_in[8],  *ln4b=(const float*)d_in[9];
  const float* ln5g =(const float*)d_in[10], *ln5b=(const float*)d_in[11];
  const float* ca_wq=(const float*)d_in[12], *ca_bq=(const float*)d_in[13];
  const float* ca_wk=(const float*)d_in[14], *ca_bk=(const float*)d_in[15];
  const float* ca_wv=(const float*)d_in[16], *ca_bv=(const float*)d_in[17];
  const float* ca_wo=(const float*)d_in[18], *ca_bo=(const float*)d_in[19];
  const float* sa_wq=(const float*)d_in[20], *sa_bq=(const float*)d_in[21];
  const float* sa_wk=(const float*)d_in[22], *sa_bk=(const float*)d_in[23];
  const float* sa_wv=(const float*)d_in[24], *sa_bv=(const float*)d_in[25];
  const float* sa_wo=(const float*)d_in[26], *sa_bo=(const float*)d_in[27];
  const float* f1w1 =(const float*)d_in[28], *f1b1=(const float*)d_in[29];
  const float* f1w2 =(const float*)d_in[30], *f1b2=(const float*)d_in[31];
  const float* f2w1 =(const float*)d_in[32], *f2b1=(const float*)d_in[33];
  const float* f2w2 =(const float*)d_in[34], *f2b2=(const float*)d_in[35];

  char* p = (char*)d_ws;
  u16*   WBF = (u16*)p;    p += 13631488;   // bf16 weights
  float* XW  = (float*)p;  p += 33554432;   // residual stream fp32 [16384,512]
  u16*   XN2 = (u16*)p;    p += 33554432;   // LN out (frag layout), up to 2x16384 rows
  u16*   QB  = (u16*)p;    p += 16777216;   // q softmax out (row-major)
  u16*   R1  = (u16*)p;    p += 67108864;   // FFN hidden (frag) OR stacked KB2|VB2 (row)
  u16*   OUTB= (u16*)p;    p += 16777216;   // attn out / x-LN staging (frag layout)
  float* SM  = (float*)p;  p += 1597440;    // ctx + ksum (zeroed)
  u16*   XN  = XN2;
  u16*   KB2 = R1;
  u16*   VB2 = R1 + 16777216;
  u16*   HB  = R1;
  float* CTXC = SM;                          // [2][32][4096]
  float* CTXS = SM + 262144;                 // [32][4096]
  float* KSC  = SM + 393216;                 // [2][4][512]
  float* KSS  = SM + 397312;                 // [4][512]

  WDesc wd;
  const float* wsrc[14] = {ca_wq, ca_wk, ca_wv, ca_wk+262144, ca_wv+262144, ca_wo,
                           sa_wq, sa_wk, sa_wv, sa_wo, f1w1, f1w2, f2w1, f2w2};
  const int    woff[14] = {0, 262144, 524288, 786432, 1048576, 1310720,
                           1572864, 1835008, 2097152, 2359296,
                           2621440, 3670016, 4718592, 5767168};
  for(int i=0;i<14;i++){ wd.src[i]=wsrc[i]; wd.off[i]=woff[i]; }
  convw_kernel<<<26624,256,0,stream>>>(wd, WBF);
  hipMemsetAsync(SM, 0, 399360*sizeof(float), stream);

  SubD zsub = {nullptr,nullptr,nullptr,0};

  // ---- cross attention ----
  ln_kernel<<<4096,256,0,stream>>>(x_in, ln1g, ln1b, OUTB);   // x-LN staged (frag) in OUTB
  lny_kernel<<<8192,256,0,stream>>>(ys, ln2g, ln2b, XN2);     // both ys LNs (frag)
  gemm_q64<<<dim3(8,128),256,0,stream>>>(OUTB, WBF+0, ca_bq, QB);
  { Subs3 s = {{ {ca_bk, KB2, KSC, 1}, {ca_bv, VB2, nullptr, 0}, zsub }};
    gemm_qkv<<<dim3(8,256),256,0,stream>>>(XN2, WBF+262144, s, 512,
                                           524288, 512, 2048); }  // i = bm>>7
  ctx_kernel<<<dim3(64,8),256,0,stream>>>(KB2, VB2, CTXC, (size_t)16384*512);
  apply_kernel<2><<<dim3(32,16),256,0,stream>>>(QB, CTXC, KSC, 1e-8f, OUTB);
  gemm_dn64<<<dim3(8,128),256,0,stream>>>(OUTB, WBF+1310720, ca_bo, x_in, XW, 512, 512);

  // ---- FFN 1 ----
  ln_kernel<<<4096,256,0,stream>>>(XW, ln3g, ln3b, XN);
  gemm_up<<<dim3(16,128),256,0,stream>>>(XN, WBF+2621440, f1b1, HB, 2048, 512);
  gemm_dn64<<<dim3(8,128),256,0,stream>>>(HB, WBF+3670016, f1b2, XW, XW, 512, 2048);

  // ---- linear self attention ----
  ln_kernel<<<4096,256,0,stream>>>(XW, ln4g, ln4b, XN);
  { Subs3 s = {{ {sa_bq, QB, nullptr, 1}, {sa_bk, KB2, KSS, 1}, {sa_bv, VB2, nullptr, 0} }};
    gemm_qkv<<<dim3(12,128),256,0,stream>>>(XN, WBF+1572864, s, 512, 0,0,0); }
  ctx_kernel<<<dim3(32,8),256,0,stream>>>(KB2, VB2, CTXS, 0);
  apply_kernel<1><<<dim3(32,16),256,0,stream>>>(QB, CTXS, KSS, 0.f, OUTB);
  gemm_dn64<<<dim3(8,128),256,0,stream>>>(OUTB, WBF+2359296, sa_bo, XW, XW, 512, 512);

  // ---- FFN 2 ----
  ln_kernel<<<4096,256,0,stream>>>(XW, ln5g, ln5b, XN);
  gemm_up<<<dim3(16,128),256,0,stream>>>(XN, WBF+4718592, f2b1, HB, 2048, 512);
  gemm_dn64<<<dim3(8,128),256,0,stream>>>(HB, WBF+5767168, f2b2, XW, (float*)d_out, 512, 2048);
}